// Round 3
// baseline (220.893 us; speedup 1.0000x reference)
//
#include <hip/hip_runtime.h>
#include <stdint.h>

#define Bd 2
#define Td 2048
#define Cd 1024
#define Hd 16
#define HDd 64
#define BT 4096

typedef _Float16 f16;
typedef __attribute__((ext_vector_type(8))) _Float16 f16x8;
typedef __attribute__((ext_vector_type(4))) _Float16 f16x4;
typedef __attribute__((ext_vector_type(2))) _Float16 f16x2;
typedef __attribute__((ext_vector_type(4))) float f32x4;
typedef __attribute__((ext_vector_type(16))) float f32x16;

#define GLD_LDS16(gptr, lptr)                                                        \
    __builtin_amdgcn_global_load_lds((const __attribute__((address_space(1))) void*)(gptr), \
                                     (__attribute__((address_space(3))) void*)(lptr), 16, 0, 0)

// ---------------- trig tables: cos/sin of freqs (T x 32) ----------------
__global__ void k_trig(const float* __restrict__ freqs, float* __restrict__ cosT,
                       float* __restrict__ sinT) {
    int i = blockIdx.x * 256 + threadIdx.x;  // 65536 total
    float f = freqs[i];
    cosT[i] = cosf(f);
    sinT[i] = sinf(f);
}

// ---------------- f32 -> f16 conversion (q,k,v,Wq,Wk,Wv,Wo) ----------------
__global__ void k_cvt(const float* __restrict__ q, const float* __restrict__ k,
                      const float* __restrict__ v, const float* __restrict__ wq,
                      const float* __restrict__ wk, const float* __restrict__ wv,
                      const float* __restrict__ wo, f16* __restrict__ qh, f16* __restrict__ kh,
                      f16* __restrict__ vh, f16* __restrict__ wqh, f16* __restrict__ wkh,
                      f16* __restrict__ wvh, f16* __restrict__ woh) {
    int g = blockIdx.x * 256 + threadIdx.x;  // float4 groups, 4194304 total
    const float* src;
    f16* dst;
    int base;
    if (g < 1048576)      { src = q;  dst = qh;  base = 0; }
    else if (g < 2097152) { src = k;  dst = kh;  base = 1048576; }
    else if (g < 3145728) { src = v;  dst = vh;  base = 2097152; }
    else if (g < 3407872) { src = wq; dst = wqh; base = 3145728; }
    else if (g < 3670016) { src = wk; dst = wkh; base = 3407872; }
    else if (g < 3932160) { src = wv; dst = wvh; base = 3670016; }
    else                  { src = wo; dst = woh; base = 3932160; }
    int i = g - base;
    float4 val = reinterpret_cast<const float4*>(src)[i];
    f16x4 o;
    o[0] = (f16)val.x; o[1] = (f16)val.y; o[2] = (f16)val.z; o[3] = (f16)val.w;
    reinterpret_cast<f16x4*>(dst)[i] = o;
}

// ---------------- GEMM: out[m][n] = sum_k A[m][k] * W[n][k]  (M=4096,N=1024,K=1024)
template <int OUT_F32>
__device__ __forceinline__ void gemm_body(const f16* __restrict__ A, const f16* __restrict__ W,
                                          void* __restrict__ out) {
    __shared__ __attribute__((aligned(16))) f16 Alds[128 * 32];
    __shared__ __attribute__((aligned(16))) f16 Blds[128 * 32];
    const int tid = threadIdx.x;
    const int lane = tid & 63, w = tid >> 6;
    const int g = lane >> 4, r15 = lane & 15;
    const int m0 = blockIdx.y * 128, n0 = blockIdx.x * 128;
    const int wm = (w >> 1) * 64, wn = (w & 1) * 64;

    const f32x4 zero4 = {0.f, 0.f, 0.f, 0.f};
    f32x4 acc[4][4];
#pragma unroll
    for (int i = 0; i < 4; ++i) {
#pragma unroll
        for (int j = 0; j < 4; ++j) acc[i][j] = zero4;
    }

    const int srow = w * 32 + (lane >> 2);  // + c*16
    const int sch = (lane & 3) * 8;

    for (int k0 = 0; k0 < Cd; k0 += 32) {
#pragma unroll
        for (int c = 0; c < 2; ++c) {
            int row = srow + c * 16;
            GLD_LDS16(A + (m0 + row) * Cd + k0 + sch, &Alds[(w * 2 + c) * 512]);
            GLD_LDS16(W + (n0 + row) * Cd + k0 + sch, &Blds[(w * 2 + c) * 512]);
        }
        __syncthreads();
        f16x8 af[4], bf[4];
#pragma unroll
        for (int t = 0; t < 4; ++t) {
            af[t] = *(const f16x8*)&Alds[(wm + t * 16 + r15) * 32 + g * 8];
            bf[t] = *(const f16x8*)&Blds[(wn + t * 16 + r15) * 32 + g * 8];
        }
#pragma unroll
        for (int i = 0; i < 4; ++i) {
#pragma unroll
            for (int j = 0; j < 4; ++j)
                acc[i][j] = __builtin_amdgcn_mfma_f32_16x16x32_f16(af[i], bf[j], acc[i][j], 0, 0, 0);
        }
        __syncthreads();
    }
#pragma unroll
    for (int i = 0; i < 4; ++i) {
#pragma unroll
        for (int j = 0; j < 4; ++j) {
#pragma unroll
            for (int r = 0; r < 4; ++r) {
                int row = m0 + wm + i * 16 + g * 4 + r;
                int col = n0 + wn + j * 16 + r15;
                if (OUT_F32)
                    ((float*)out)[row * Cd + col] = acc[i][j][r];
                else
                    ((f16*)out)[row * Cd + col] = (f16)acc[i][j][r];
            }
        }
    }
}

__global__ __launch_bounds__(256) void k_gemm_qkv(const f16* qh, const f16* kh, const f16* vh,
                                                  const f16* wqh, const f16* wkh, const f16* wvh,
                                                  f16* Qp, f16* Kp, f16* Vp) {
    int z = blockIdx.z;
    const f16* A = (z == 0) ? qh : (z == 1) ? kh : vh;
    const f16* W = (z == 0) ? wqh : (z == 1) ? wkh : wvh;
    f16* out = (z == 0) ? Qp : (z == 1) ? Kp : Vp;
    gemm_body<0>(A, W, out);
}

__global__ __launch_bounds__(256) void k_gemm_out(const f16* yh, const f16* woh, float* out) {
    gemm_body<1>(yh, woh, out);
}

// ---------------- RoPE in-place on Qp, Kp ----------------
__global__ void k_rope(f16* __restrict__ Qp, f16* __restrict__ Kp, const float* __restrict__ cosT,
                       const float* __restrict__ sinT) {
    int idx = blockIdx.x * 256 + threadIdx.x;  // 2 * 524288
    f16* ptr = (idx < 524288) ? Qp : Kp;
    int i = idx & 524287;
    int gi = i & 7;     // 8-elem group within head dim
    int bth = i >> 3;   // bt*16 + h
    int h = bth & 15;
    int bt = bth >> 4;
    int t = bt & 2047;
    int off = bt * 1024 + h * 64 + gi * 8;
    f16x8 v = *(f16x8*)(ptr + off);
    float4 c4 = *(const float4*)&cosT[t * 32 + gi * 4];
    float4 s4 = *(const float4*)&sinT[t * 32 + gi * 4];
    f16x8 o;
    float x0, x1;
    x0 = (float)v[0]; x1 = (float)v[1];
    o[0] = (f16)(x0 * c4.x - x1 * s4.x); o[1] = (f16)(x0 * s4.x + x1 * c4.x);
    x0 = (float)v[2]; x1 = (float)v[3];
    o[2] = (f16)(x0 * c4.y - x1 * s4.y); o[3] = (f16)(x0 * s4.y + x1 * c4.y);
    x0 = (float)v[4]; x1 = (float)v[5];
    o[4] = (f16)(x0 * c4.z - x1 * s4.z); o[5] = (f16)(x0 * s4.z + x1 * c4.z);
    x0 = (float)v[6]; x1 = (float)v[7];
    o[6] = (f16)(x0 * c4.w - x1 * s4.w); o[7] = (f16)(x0 * s4.w + x1 * c4.w);
    *(f16x8*)(ptr + off) = o;
}

// ---------------- V transpose: Vp[bt][h*64+d] -> Vt[bh][d][t] ----------------
__global__ void k_vtrans(const f16* __restrict__ Vp, f16* __restrict__ Vt) {
    __shared__ __attribute__((aligned(16))) f16 tile[64][72];
    int bh = blockIdx.y, b = bh >> 4, h = bh & 15;
    int t0 = blockIdx.x * 64;
    int tid = threadIdx.x;
#pragma unroll
    for (int c = 0; c < 2; ++c) {
        int id = c * 256 + tid;
        int row = id >> 3, ch = id & 7;
        *(f16x8*)&tile[row][ch * 8] =
            *(const f16x8*)(Vp + (b * 2048 + t0 + row) * 1024 + h * 64 + ch * 8);
    }
    __syncthreads();
#pragma unroll
    for (int c = 0; c < 2; ++c) {
        int id = c * 256 + tid;
        int d = id & 63, tch = id >> 6;  // d = lane within wave -> conflict-free LDS reads
        f16x8 vv;
#pragma unroll
        for (int j = 0; j < 8; ++j) vv[j] = tile[tch * 8 + j][d];
        *(f16x8*)(Vt + (bh * 64 + d) * 2048 + t0 + tch * 8) = vv;
    }
}

// ---------------- Flash attention: KVBLK=64, counted-vmcnt 2-barrier pipeline ----------------
// grid: x = bh (32) so the 8 q-blocks of one bh land on the SAME XCD (linear-id step 32 % 8 == 0),
//       y = q-block (8). 512 threads = 8 waves x 32 q-rows. Softmax in log2 domain (Q pre-scaled
//       by 0.125*log2e), defer-max rescale (THR=8 -> P <= 256, f16-safe).
__global__ __launch_bounds__(512, 2) void k_flash(const f16* __restrict__ Qp,
                                                  const f16* __restrict__ Kp,
                                                  const f16* __restrict__ Vt,
                                                  f16* __restrict__ y) {
    __shared__ __attribute__((aligned(16))) f16 Klds[2 * 4096];  // [buf][64 kv][64 d] src-swizzled
    __shared__ __attribute__((aligned(16))) f16 Vlds[2 * 4096];  // [buf][64 d][64 kv] src-swizzled
    const int bh = blockIdx.x, b = bh >> 4, h = bh & 15;
    const int tid = threadIdx.x, lane = tid & 63, w = tid >> 6;
    const int r31 = lane & 31, hi = lane >> 5;

    // staging: thread t covers slot t (16B); row = t>>3, chunk j = t&7. Global source chunk is
    // pre-XOR-swizzled (j ^ (row&7)) so frag reads use the same involution (m173 both-sides).
    const int srow = tid >> 3, sj = tid & 7;
    const f16* gK = Kp + (b * 2048 + srow) * 1024 + h * 64 + ((sj ^ (srow & 7)) * 8);
    const f16* gV = Vt + (bh * 64 + srow) * 2048 + ((sj ^ (srow & 7)) * 8);
    f16* lK = (f16*)Klds + w * 512;  // wave-uniform base; lane writes base + lane*16B
    f16* lV = (f16*)Vlds + w * 512;

    // Q fragments (B-operand of mfma(K,Q)); 0.125 = 1/sqrt(64), log2e folds exp->exp2
    f16x8 qf[4];
    {
        const f16* qb =
            Qp + (b * 2048 + blockIdx.y * 256 + w * 32 + r31) * 1024 + h * 64 + hi * 8;
        const f16 sc = (f16)(0.125f * 1.44269504088896f);
#pragma unroll
        for (int dc = 0; dc < 4; ++dc) {
            f16x8 v = *(const f16x8*)(qb + dc * 16);
#pragma unroll
            for (int j = 0; j < 8; ++j) v[j] = v[j] * sc;
            qf[dc] = v;
        }
    }

    f32x16 o0, o1;
#pragma unroll
    for (int r = 0; r < 16; ++r) { o0[r] = 0.f; o1[r] = 0.f; }
    float m = -1e30f, l = 0.f;

    // prologue: stage tile 0 -> buf0
    GLD_LDS16(gK, lK);
    GLD_LDS16(gV, lV);

    for (int t = 0; t < 32; ++t) {
        __builtin_amdgcn_s_barrier();  // all waves done reading buf[(t+1)&1] (tile t-1)
        if (t < 31) {
            GLD_LDS16(gK + (t + 1) * 65536, lK + ((t + 1) & 1) * 4096);
            GLD_LDS16(gV + (t + 1) * 64, lV + ((t + 1) & 1) * 4096);
            asm volatile("s_waitcnt vmcnt(2)" ::: "memory");  // own tile-t loads done; t+1 in flight
        } else {
            asm volatile("s_waitcnt vmcnt(0)" ::: "memory");
        }
        __builtin_amdgcn_s_barrier();  // everyone's tile-t stage complete
        const f16* Kb = (const f16*)Klds + (t & 1) * 4096;
        const f16* Vb = (const f16*)Vlds + (t & 1) * 4096;

        // S^T[kv 64][q 32] = K_tile . Q^T  (lane: col q=r31; rows (r&3)+8*(r>>2)+4*hi (+32))
        f32x16 s0, s1;
#pragma unroll
        for (int r = 0; r < 16; ++r) { s0[r] = 0.f; s1[r] = 0.f; }
        __builtin_amdgcn_s_setprio(1);
#pragma unroll
        for (int dc = 0; dc < 4; ++dc) {
            int j = (2 * dc + hi) ^ (r31 & 7);
            f16x8 k0 = *(const f16x8*)&Kb[r31 * 64 + j * 8];
            f16x8 k1 = *(const f16x8*)&Kb[(32 + r31) * 64 + j * 8];
            s0 = __builtin_amdgcn_mfma_f32_32x32x16_f16(k0, qf[dc], s0, 0, 0, 0);
            s1 = __builtin_amdgcn_mfma_f32_32x32x16_f16(k1, qf[dc], s1, 0, 0, 0);
        }
        __builtin_amdgcn_s_setprio(0);

        // online softmax (log2 domain), defer-max: skip O-rescale while growth <= 8
        float t16[16];
#pragma unroll
        for (int r = 0; r < 16; ++r) t16[r] = fmaxf(s0[r], s1[r]);
#pragma unroll
        for (int r = 0; r < 8; ++r) t16[r] = fmaxf(t16[r], t16[r + 8]);
#pragma unroll
        for (int r = 0; r < 4; ++r) t16[r] = fmaxf(t16[r], t16[r + 4]);
        float pmax = fmaxf(fmaxf(t16[0], t16[1]), fmaxf(t16[2], t16[3]));
        pmax = fmaxf(pmax, __shfl_xor(pmax, 32, 64));
        if (__any(pmax > m + 8.0f)) {
            float mn = fmaxf(m, pmax);
            float cr = exp2f(m - mn);
            m = mn;
            l *= cr;
#pragma unroll
            for (int r = 0; r < 16; ++r) { o0[r] *= cr; o1[r] *= cr; }
        }
        float rs = 0.f;
#pragma unroll
        for (int r = 0; r < 16; ++r) { float p = exp2f(s0[r] - m); s0[r] = p; rs += p; }
#pragma unroll
        for (int r = 0; r < 16; ++r) { float p = exp2f(s1[r] - m); s1[r] = p; rs += p; }
        rs += __shfl_xor(rs, 32, 64);
        l += rs;

        // pack P pairs to f16; partner-exchange builds PV B-operand in-register
        unsigned pk[16], xk[16];
#pragma unroll
        for (int i = 0; i < 8; ++i) {
            auto ha = __builtin_amdgcn_cvt_pkrtz(s0[2 * i], s0[2 * i + 1]);
            __builtin_memcpy(&pk[i], &ha, 4);
            auto hb = __builtin_amdgcn_cvt_pkrtz(s1[2 * i], s1[2 * i + 1]);
            __builtin_memcpy(&pk[8 + i], &hb, 4);
        }
#pragma unroll
        for (int i = 0; i < 16; ++i) xk[i] = (unsigned)__shfl_xor((int)pk[i], 32, 64);

        // O^T[d][q] += V^T[d][kv] P[kv][q]; kv k-slices s=0..3 (16 each)
        __builtin_amdgcn_s_setprio(1);
#pragma unroll
        for (int s = 0; s < 4; ++s) {
            int a0 = (s >> 1) * 8 + (s & 1) * 4 + hi * 2;
            union { unsigned u[4]; f16x8 v; } uv;
            uv.u[0] = hi ? xk[a0] : pk[a0];
            uv.u[1] = hi ? xk[a0 + 1] : pk[a0 + 1];
            uv.u[2] = hi ? pk[a0] : xk[a0];
            uv.u[3] = hi ? pk[a0 + 1] : xk[a0 + 1];
            int j = (2 * s + hi) ^ (r31 & 7);
            f16x8 v0 = *(const f16x8*)&Vb[r31 * 64 + j * 8];
            f16x8 v1 = *(const f16x8*)&Vb[(32 + r31) * 64 + j * 8];
            o0 = __builtin_amdgcn_mfma_f32_32x32x16_f16(v0, uv.v, o0, 0, 0, 0);
            o1 = __builtin_amdgcn_mfma_f32_32x32x16_f16(v1, uv.v, o1, 0, 0, 0);
        }
        __builtin_amdgcn_s_setprio(0);
    }

    // epilogue: lane holds O^T[d=(r&3)+8*(r>>2)+4*hi (+32)][q=r31]; normalize + store
    float inv = 1.0f / l;
    f16* yb = y + (b * 2048 + blockIdx.y * 256 + w * 32 + r31) * 1024 + h * 64 + hi * 4;
#pragma unroll
    for (int rg = 0; rg < 4; ++rg) {
        f16x4 ov;
#pragma unroll
        for (int i = 0; i < 4; ++i) ov[i] = (f16)(o0[rg * 4 + i] * inv);
        *(f16x4*)&yb[rg * 8] = ov;
#pragma unroll
        for (int i = 0; i < 4; ++i) ov[i] = (f16)(o1[rg * 4 + i] * inv);
        *(f16x4*)&yb[32 + rg * 8] = ov;
    }
}

extern "C" void kernel_launch(void* const* d_in, const int* in_sizes, int n_in, void* d_out,
                              int out_size, void* d_ws, size_t ws_size, hipStream_t stream) {
    const float* q = (const float*)d_in[0];
    const float* k = (const float*)d_in[1];
    const float* v = (const float*)d_in[2];
    const float* fr = (const float*)d_in[3];
    const float* wq = (const float*)d_in[4];
    const float* wk = (const float*)d_in[5];
    const float* wv = (const float*)d_in[6];
    const float* wo = (const float*)d_in[7];
    char* ws = (char*)d_ws;

    float* cosT = (float*)(ws + 0);
    float* sinT = (float*)(ws + 262144);
    f16* qh = (f16*)(ws + 524288);
    f16* kh = (f16*)(ws + 8912896);
    f16* vh = (f16*)(ws + 17301504);
    f16* wqh = (f16*)(ws + 25690112);
    f16* wkh = (f16*)(ws + 27787264);
    f16* wvh = (f16*)(ws + 29884416);
    f16* woh = (f16*)(ws + 31981568);
    f16* Qp = (f16*)(ws + 34078720);
    f16* Kp = (f16*)(ws + 42467328);
    f16* Vp = (f16*)(ws + 50855936);
    // qh/kh are dead after the QKV GEMM: alias Vt and y over them
    f16* Vt = (f16*)(ws + 524288);
    f16* yh = (f16*)(ws + 8912896);

    k_trig<<<256, 256, 0, stream>>>(fr, cosT, sinT);
    k_cvt<<<16384, 256, 0, stream>>>(q, k, v, wq, wk, wv, wo, qh, kh, vh, wqh, wkh, wvh, woh);
    dim3 gq(8, 32, 3);
    k_gemm_qkv<<<gq, 256, 0, stream>>>(qh, kh, vh, wqh, wkh, wvh, Qp, Kp, Vp);
    k_rope<<<4096, 256, 0, stream>>>(Qp, Kp, cosT, sinT);
    dim3 gt(32, 32);
    k_vtrans<<<gt, 256, 0, stream>>>(Vp, Vt);
    dim3 gf(32, 8);
    k_flash<<<gf, 512, 0, stream>>>(Qp, Kp, Vt, yh);
    dim3 go(8, 32);
    k_gemm_out<<<go, 256, 0, stream>>>(yh, woh, (float*)d_out);
}

// Round 4
// 176.588 us; speedup vs baseline: 1.2509x; 1.2509x over previous
//
#include <hip/hip_runtime.h>
#include <stdint.h>

#define Bd 2
#define Td 2048
#define Cd 1024
#define Hd 16
#define HDd 64
#define BT 4096

typedef _Float16 f16;
typedef __attribute__((ext_vector_type(8))) _Float16 f16x8;
typedef __attribute__((ext_vector_type(4))) _Float16 f16x4;
typedef __attribute__((ext_vector_type(2))) _Float16 f16x2;
typedef __attribute__((ext_vector_type(4))) float f32x4;
typedef __attribute__((ext_vector_type(16))) float f32x16;

#define GLD_LDS16(gptr, lptr)                                                        \
    __builtin_amdgcn_global_load_lds((const __attribute__((address_space(1))) void*)(gptr), \
                                     (__attribute__((address_space(3))) void*)(lptr), 16, 0, 0)

// ---------------- trig tables: cos/sin of freqs (T x 32) ----------------
__global__ void k_trig(const float* __restrict__ freqs, float* __restrict__ cosT,
                       float* __restrict__ sinT) {
    int i = blockIdx.x * 256 + threadIdx.x;  // 65536 total
    float f = freqs[i];
    cosT[i] = cosf(f);
    sinT[i] = sinf(f);
}

// ---------------- f32 -> f16 conversion (q,k,v,Wq,Wk,Wv,Wo) ----------------
__global__ void k_cvt(const float* __restrict__ q, const float* __restrict__ k,
                      const float* __restrict__ v, const float* __restrict__ wq,
                      const float* __restrict__ wk, const float* __restrict__ wv,
                      const float* __restrict__ wo, f16* __restrict__ qh, f16* __restrict__ kh,
                      f16* __restrict__ vh, f16* __restrict__ wqh, f16* __restrict__ wkh,
                      f16* __restrict__ wvh, f16* __restrict__ woh) {
    int g = blockIdx.x * 256 + threadIdx.x;  // float4 groups, 4194304 total
    const float* src;
    f16* dst;
    int base;
    if (g < 1048576)      { src = q;  dst = qh;  base = 0; }
    else if (g < 2097152) { src = k;  dst = kh;  base = 1048576; }
    else if (g < 3145728) { src = v;  dst = vh;  base = 2097152; }
    else if (g < 3407872) { src = wq; dst = wqh; base = 3145728; }
    else if (g < 3670016) { src = wk; dst = wkh; base = 3407872; }
    else if (g < 3932160) { src = wv; dst = wvh; base = 3670016; }
    else                  { src = wo; dst = woh; base = 3932160; }
    int i = g - base;
    float4 val = reinterpret_cast<const float4*>(src)[i];
    f16x4 o;
    o[0] = (f16)val.x; o[1] = (f16)val.y; o[2] = (f16)val.z; o[3] = (f16)val.w;
    reinterpret_cast<f16x4*>(dst)[i] = o;
}

// ---------------- GEMM: out[m][n] = sum_k A[m][k] * W[n][k]  (M=4096,N=1024,K=1024)
template <int OUT_F32>
__device__ __forceinline__ void gemm_body(const f16* __restrict__ A, const f16* __restrict__ W,
                                          void* __restrict__ out) {
    __shared__ __attribute__((aligned(16))) f16 Alds[128 * 32];
    __shared__ __attribute__((aligned(16))) f16 Blds[128 * 32];
    const int tid = threadIdx.x;
    const int lane = tid & 63, w = tid >> 6;
    const int g = lane >> 4, r15 = lane & 15;
    const int m0 = blockIdx.y * 128, n0 = blockIdx.x * 128;
    const int wm = (w >> 1) * 64, wn = (w & 1) * 64;

    const f32x4 zero4 = {0.f, 0.f, 0.f, 0.f};
    f32x4 acc[4][4];
#pragma unroll
    for (int i = 0; i < 4; ++i) {
#pragma unroll
        for (int j = 0; j < 4; ++j) acc[i][j] = zero4;
    }

    const int srow = w * 32 + (lane >> 2);  // + c*16
    const int sch = (lane & 3) * 8;

    for (int k0 = 0; k0 < Cd; k0 += 32) {
#pragma unroll
        for (int c = 0; c < 2; ++c) {
            int row = srow + c * 16;
            GLD_LDS16(A + (m0 + row) * Cd + k0 + sch, &Alds[(w * 2 + c) * 512]);
            GLD_LDS16(W + (n0 + row) * Cd + k0 + sch, &Blds[(w * 2 + c) * 512]);
        }
        __syncthreads();
        f16x8 af[4], bf[4];
#pragma unroll
        for (int t = 0; t < 4; ++t) {
            af[t] = *(const f16x8*)&Alds[(wm + t * 16 + r15) * 32 + g * 8];
            bf[t] = *(const f16x8*)&Blds[(wn + t * 16 + r15) * 32 + g * 8];
        }
#pragma unroll
        for (int i = 0; i < 4; ++i) {
#pragma unroll
            for (int j = 0; j < 4; ++j)
                acc[i][j] = __builtin_amdgcn_mfma_f32_16x16x32_f16(af[i], bf[j], acc[i][j], 0, 0, 0);
        }
        __syncthreads();
    }
#pragma unroll
    for (int i = 0; i < 4; ++i) {
#pragma unroll
        for (int j = 0; j < 4; ++j) {
#pragma unroll
            for (int r = 0; r < 4; ++r) {
                int row = m0 + wm + i * 16 + g * 4 + r;
                int col = n0 + wn + j * 16 + r15;
                if (OUT_F32)
                    ((float*)out)[row * Cd + col] = acc[i][j][r];
                else
                    ((f16*)out)[row * Cd + col] = (f16)acc[i][j][r];
            }
        }
    }
}

__global__ __launch_bounds__(256) void k_gemm_qkv(const f16* qh, const f16* kh, const f16* vh,
                                                  const f16* wqh, const f16* wkh, const f16* wvh,
                                                  f16* Qp, f16* Kp, f16* Vp) {
    int z = blockIdx.z;
    const f16* A = (z == 0) ? qh : (z == 1) ? kh : vh;
    const f16* W = (z == 0) ? wqh : (z == 1) ? wkh : wvh;
    f16* out = (z == 0) ? Qp : (z == 1) ? Kp : Vp;
    gemm_body<0>(A, W, out);
}

__global__ __launch_bounds__(256) void k_gemm_out(const f16* yh, const f16* woh, float* out) {
    gemm_body<1>(yh, woh, out);
}

// ---------------- RoPE in-place on Qp, Kp ----------------
__global__ void k_rope(f16* __restrict__ Qp, f16* __restrict__ Kp, const float* __restrict__ cosT,
                       const float* __restrict__ sinT) {
    int idx = blockIdx.x * 256 + threadIdx.x;  // 2 * 524288
    f16* ptr = (idx < 524288) ? Qp : Kp;
    int i = idx & 524287;
    int gi = i & 7;     // 8-elem group within head dim
    int bth = i >> 3;   // bt*16 + h
    int h = bth & 15;
    int bt = bth >> 4;
    int t = bt & 2047;
    int off = bt * 1024 + h * 64 + gi * 8;
    f16x8 v = *(f16x8*)(ptr + off);
    float4 c4 = *(const float4*)&cosT[t * 32 + gi * 4];
    float4 s4 = *(const float4*)&sinT[t * 32 + gi * 4];
    f16x8 o;
    float x0, x1;
    x0 = (float)v[0]; x1 = (float)v[1];
    o[0] = (f16)(x0 * c4.x - x1 * s4.x); o[1] = (f16)(x0 * s4.x + x1 * c4.x);
    x0 = (float)v[2]; x1 = (float)v[3];
    o[2] = (f16)(x0 * c4.y - x1 * s4.y); o[3] = (f16)(x0 * s4.y + x1 * c4.y);
    x0 = (float)v[4]; x1 = (float)v[5];
    o[4] = (f16)(x0 * c4.z - x1 * s4.z); o[5] = (f16)(x0 * s4.z + x1 * c4.z);
    x0 = (float)v[6]; x1 = (float)v[7];
    o[6] = (f16)(x0 * c4.w - x1 * s4.w); o[7] = (f16)(x0 * s4.w + x1 * c4.w);
    *(f16x8*)(ptr + off) = o;
}

// ---------------- V transpose: Vp[bt][h*64+d] -> Vt[bh][d][t] ----------------
__global__ void k_vtrans(const f16* __restrict__ Vp, f16* __restrict__ Vt) {
    __shared__ __attribute__((aligned(16))) f16 tile[64][72];
    int bh = blockIdx.y, b = bh >> 4, h = bh & 15;
    int t0 = blockIdx.x * 64;
    int tid = threadIdx.x;
#pragma unroll
    for (int c = 0; c < 2; ++c) {
        int id = c * 256 + tid;
        int row = id >> 3, ch = id & 7;
        *(f16x8*)&tile[row][ch * 8] =
            *(const f16x8*)(Vp + (b * 2048 + t0 + row) * 1024 + h * 64 + ch * 8);
    }
    __syncthreads();
#pragma unroll
    for (int c = 0; c < 2; ++c) {
        int id = c * 256 + tid;
        int d = id & 63, tch = id >> 6;  // d = lane within wave -> conflict-free LDS reads
        f16x8 vv;
#pragma unroll
        for (int j = 0; j < 8; ++j) vv[j] = tile[tch * 8 + j][d];
        *(f16x8*)(Vt + (bh * 64 + d) * 2048 + t0 + tch * 8) = vv;
    }
}

// ---------------- Flash attention: KVBLK=64, counted-vmcnt 2-barrier pipeline ----------------
// grid: x = bh (32) so the 8 q-blocks of one bh land on the SAME XCD (linear-id step 32 % 8 == 0),
//       y = q-block (8). 512 threads = 8 waves x 32 q-rows. Softmax in log2 domain (Q pre-scaled
//       by 0.125*log2e), defer-max rescale (THR=8 -> P <= 256, f16-safe).
// NOTE: every register-array index below MUST be compile-time constant (rule #20) — R3's
// runtime-hi index demoted pk/xk to scratch (197MB write traffic, 1.65x regression).
__global__ __launch_bounds__(512, 2) void k_flash(const f16* __restrict__ Qp,
                                                  const f16* __restrict__ Kp,
                                                  const f16* __restrict__ Vt,
                                                  f16* __restrict__ y) {
    __shared__ __attribute__((aligned(16))) f16 Klds[2 * 4096];  // [buf][64 kv][64 d] src-swizzled
    __shared__ __attribute__((aligned(16))) f16 Vlds[2 * 4096];  // [buf][64 d][64 kv] src-swizzled
    const int bh = blockIdx.x, b = bh >> 4, h = bh & 15;
    const int tid = threadIdx.x, lane = tid & 63, w = tid >> 6;
    const int r31 = lane & 31, hi = lane >> 5;

    // staging: thread t covers slot t (16B); row = t>>3, chunk j = t&7. Global source chunk is
    // pre-XOR-swizzled (j ^ (row&7)) so frag reads use the same involution (m173 both-sides).
    const int srow = tid >> 3, sj = tid & 7;
    const f16* gK = Kp + (b * 2048 + srow) * 1024 + h * 64 + ((sj ^ (srow & 7)) * 8);
    const f16* gV = Vt + (bh * 64 + srow) * 2048 + ((sj ^ (srow & 7)) * 8);
    f16* lK = (f16*)Klds + w * 512;  // wave-uniform base; lane writes base + lane*16B
    f16* lV = (f16*)Vlds + w * 512;

    // Q fragments (B-operand of mfma(K,Q)); 0.125 = 1/sqrt(64), log2e folds exp->exp2
    f16x8 qf[4];
    {
        const f16* qb =
            Qp + (b * 2048 + blockIdx.y * 256 + w * 32 + r31) * 1024 + h * 64 + hi * 8;
        const f16 sc = (f16)(0.125f * 1.44269504088896f);
#pragma unroll
        for (int dc = 0; dc < 4; ++dc) {
            f16x8 v = *(const f16x8*)(qb + dc * 16);
#pragma unroll
            for (int j = 0; j < 8; ++j) v[j] = v[j] * sc;
            qf[dc] = v;
        }
    }

    f32x16 o0, o1;
#pragma unroll
    for (int r = 0; r < 16; ++r) { o0[r] = 0.f; o1[r] = 0.f; }
    float m = -1e30f, l = 0.f;

    // prologue: stage tile 0 -> buf0
    GLD_LDS16(gK, lK);
    GLD_LDS16(gV, lV);

    for (int t = 0; t < 32; ++t) {
        __builtin_amdgcn_s_barrier();  // all waves done reading buf[(t+1)&1] (tile t-1)
        if (t < 31) {
            GLD_LDS16(gK + (t + 1) * 65536, lK + ((t + 1) & 1) * 4096);
            GLD_LDS16(gV + (t + 1) * 64, lV + ((t + 1) & 1) * 4096);
            asm volatile("s_waitcnt vmcnt(2)" ::: "memory");  // own tile-t loads done; t+1 in flight
        } else {
            asm volatile("s_waitcnt vmcnt(0)" ::: "memory");
        }
        __builtin_amdgcn_sched_barrier(0);
        __builtin_amdgcn_s_barrier();  // everyone's tile-t stage complete
        const f16* Kb = (const f16*)Klds + (t & 1) * 4096;
        const f16* Vb = (const f16*)Vlds + (t & 1) * 4096;

        // S^T[kv 64][q 32] = K_tile . Q^T  (lane: col q=r31; rows (r&3)+8*(r>>2)+4*hi (+32))
        f32x16 s0, s1;
#pragma unroll
        for (int r = 0; r < 16; ++r) { s0[r] = 0.f; s1[r] = 0.f; }
        __builtin_amdgcn_s_setprio(1);
#pragma unroll
        for (int dc = 0; dc < 4; ++dc) {
            int j = (2 * dc + hi) ^ (r31 & 7);
            f16x8 k0 = *(const f16x8*)&Kb[r31 * 64 + j * 8];
            f16x8 k1 = *(const f16x8*)&Kb[(32 + r31) * 64 + j * 8];
            s0 = __builtin_amdgcn_mfma_f32_32x32x16_f16(k0, qf[dc], s0, 0, 0, 0);
            s1 = __builtin_amdgcn_mfma_f32_32x32x16_f16(k1, qf[dc], s1, 0, 0, 0);
        }
        __builtin_amdgcn_s_setprio(0);

        // online softmax (log2 domain), defer-max: skip O-rescale while growth <= 8
        float t16[16];
#pragma unroll
        for (int r = 0; r < 16; ++r) t16[r] = fmaxf(s0[r], s1[r]);
#pragma unroll
        for (int r = 0; r < 8; ++r) t16[r] = fmaxf(t16[r], t16[r + 8]);
#pragma unroll
        for (int r = 0; r < 4; ++r) t16[r] = fmaxf(t16[r], t16[r + 4]);
        float pmax = fmaxf(fmaxf(t16[0], t16[1]), fmaxf(t16[2], t16[3]));
        pmax = fmaxf(pmax, __shfl_xor(pmax, 32, 64));
        if (__any(pmax > m + 8.0f)) {
            float mn = fmaxf(m, pmax);
            float cr = exp2f(m - mn);
            m = mn;
            l *= cr;
#pragma unroll
            for (int r = 0; r < 16; ++r) { o0[r] *= cr; o1[r] *= cr; }
        }
        float rs = 0.f;
#pragma unroll
        for (int r = 0; r < 16; ++r) { float p = exp2f(s0[r] - m); s0[r] = p; rs += p; }
#pragma unroll
        for (int r = 0; r < 16; ++r) { float p = exp2f(s1[r] - m); s1[r] = p; rs += p; }
        rs += __shfl_xor(rs, 32, 64);
        l += rs;

        // pack P pairs to f16; partner-exchange builds PV B-operand in-register
        unsigned pk[16], xk[16];
#pragma unroll
        for (int i = 0; i < 8; ++i) {
            auto ha = __builtin_amdgcn_cvt_pkrtz(s0[2 * i], s0[2 * i + 1]);
            __builtin_memcpy(&pk[i], &ha, 4);
            auto hb = __builtin_amdgcn_cvt_pkrtz(s1[2 * i], s1[2 * i + 1]);
            __builtin_memcpy(&pk[8 + i], &hb, 4);
        }
#pragma unroll
        for (int i = 0; i < 16; ++i) xk[i] = (unsigned)__shfl_xor((int)pk[i], 32, 64);

        // O^T[d][q] += V^T[d][kv] P[kv][q]; kv k-slices s=0..3 (16 each).
        // All pk/xk indices are literals after unroll (base = 0,4,8,12); hi only in ternaries.
        __builtin_amdgcn_s_setprio(1);
#pragma unroll
        for (int s = 0; s < 4; ++s) {
            const int base = (s >> 1) * 8 + (s & 1) * 4;
            union { unsigned u[4]; f16x8 v; } uv;
            uv.u[0] = hi ? xk[base + 2] : pk[base + 0];
            uv.u[1] = hi ? xk[base + 3] : pk[base + 1];
            uv.u[2] = hi ? pk[base + 2] : xk[base + 0];
            uv.u[3] = hi ? pk[base + 3] : xk[base + 1];
            int j = (2 * s + hi) ^ (r31 & 7);
            f16x8 v0 = *(const f16x8*)&Vb[r31 * 64 + j * 8];
            f16x8 v1 = *(const f16x8*)&Vb[(32 + r31) * 64 + j * 8];
            o0 = __builtin_amdgcn_mfma_f32_32x32x16_f16(v0, uv.v, o0, 0, 0, 0);
            o1 = __builtin_amdgcn_mfma_f32_32x32x16_f16(v1, uv.v, o1, 0, 0, 0);
        }
        __builtin_amdgcn_s_setprio(0);
    }

    // epilogue: lane holds O^T[d=(r&3)+8*(r>>2)+4*hi (+32)][q=r31]; normalize + store
    float inv = 1.0f / l;
    f16* yb = y + (b * 2048 + blockIdx.y * 256 + w * 32 + r31) * 1024 + h * 64 + hi * 4;
#pragma unroll
    for (int rg = 0; rg < 4; ++rg) {
        f16x4 ov;
#pragma unroll
        for (int i = 0; i < 4; ++i) ov[i] = (f16)(o0[rg * 4 + i] * inv);
        *(f16x4*)&yb[rg * 8] = ov;
#pragma unroll
        for (int i = 0; i < 4; ++i) ov[i] = (f16)(o1[rg * 4 + i] * inv);
        *(f16x4*)&yb[32 + rg * 8] = ov;
    }
}

extern "C" void kernel_launch(void* const* d_in, const int* in_sizes, int n_in, void* d_out,
                              int out_size, void* d_ws, size_t ws_size, hipStream_t stream) {
    const float* q = (const float*)d_in[0];
    const float* k = (const float*)d_in[1];
    const float* v = (const float*)d_in[2];
    const float* fr = (const float*)d_in[3];
    const float* wq = (const float*)d_in[4];
    const float* wk = (const float*)d_in[5];
    const float* wv = (const float*)d_in[6];
    const float* wo = (const float*)d_in[7];
    char* ws = (char*)d_ws;

    float* cosT = (float*)(ws + 0);
    float* sinT = (float*)(ws + 262144);
    f16* qh = (f16*)(ws + 524288);
    f16* kh = (f16*)(ws + 8912896);
    f16* vh = (f16*)(ws + 17301504);
    f16* wqh = (f16*)(ws + 25690112);
    f16* wkh = (f16*)(ws + 27787264);
    f16* wvh = (f16*)(ws + 29884416);
    f16* woh = (f16*)(ws + 31981568);
    f16* Qp = (f16*)(ws + 34078720);
    f16* Kp = (f16*)(ws + 42467328);
    f16* Vp = (f16*)(ws + 50855936);
    // qh/kh are dead after the QKV GEMM: alias Vt and y over them
    f16* Vt = (f16*)(ws + 524288);
    f16* yh = (f16*)(ws + 8912896);

    k_trig<<<256, 256, 0, stream>>>(fr, cosT, sinT);
    k_cvt<<<16384, 256, 0, stream>>>(q, k, v, wq, wk, wv, wo, qh, kh, vh, wqh, wkh, wvh, woh);
    dim3 gq(8, 32, 3);
    k_gemm_qkv<<<gq, 256, 0, stream>>>(qh, kh, vh, wqh, wkh, wvh, Qp, Kp, Vp);
    k_rope<<<4096, 256, 0, stream>>>(Qp, Kp, cosT, sinT);
    dim3 gt(32, 32);
    k_vtrans<<<gt, 256, 0, stream>>>(Vp, Vt);
    dim3 gf(32, 8);
    k_flash<<<gf, 512, 0, stream>>>(Qp, Kp, Vt, yh);
    dim3 go(8, 32);
    k_gemm_out<<<go, 256, 0, stream>>>(yh, woh, (float*)d_out);
}

// Round 5
// 170.918 us; speedup vs baseline: 1.2924x; 1.0332x over previous
//
#include <hip/hip_runtime.h>
#include <stdint.h>

#define Bd 2
#define Td 2048
#define Cd 1024
#define Hd 16
#define HDd 64
#define BT 4096

typedef _Float16 f16;
typedef __attribute__((ext_vector_type(8))) _Float16 f16x8;
typedef __attribute__((ext_vector_type(4))) _Float16 f16x4;
typedef __attribute__((ext_vector_type(2))) _Float16 f16x2;
typedef __attribute__((ext_vector_type(4))) float f32x4;
typedef __attribute__((ext_vector_type(16))) float f32x16;

#define GLD_LDS16(gptr, lptr)                                                        \
    __builtin_amdgcn_global_load_lds((const __attribute__((address_space(1))) void*)(gptr), \
                                     (__attribute__((address_space(3))) void*)(lptr), 16, 0, 0)

#define MAX3(a, b, c) fmaxf(fmaxf(a, b), c)

// ---------------- trig tables: cos/sin of freqs (T x 32) ----------------
__global__ void k_trig(const float* __restrict__ freqs, float* __restrict__ cosT,
                       float* __restrict__ sinT) {
    int i = blockIdx.x * 256 + threadIdx.x;  // 65536 total
    float f = freqs[i];
    cosT[i] = cosf(f);
    sinT[i] = sinf(f);
}

// ---------------- f32 -> f16 conversion (q,k,v,Wq,Wk,Wv,Wo) ----------------
__global__ void k_cvt(const float* __restrict__ q, const float* __restrict__ k,
                      const float* __restrict__ v, const float* __restrict__ wq,
                      const float* __restrict__ wk, const float* __restrict__ wv,
                      const float* __restrict__ wo, f16* __restrict__ qh, f16* __restrict__ kh,
                      f16* __restrict__ vh, f16* __restrict__ wqh, f16* __restrict__ wkh,
                      f16* __restrict__ wvh, f16* __restrict__ woh) {
    int g = blockIdx.x * 256 + threadIdx.x;  // float4 groups, 4194304 total
    const float* src;
    f16* dst;
    int base;
    if (g < 1048576)      { src = q;  dst = qh;  base = 0; }
    else if (g < 2097152) { src = k;  dst = kh;  base = 1048576; }
    else if (g < 3145728) { src = v;  dst = vh;  base = 2097152; }
    else if (g < 3407872) { src = wq; dst = wqh; base = 3145728; }
    else if (g < 3670016) { src = wk; dst = wkh; base = 3407872; }
    else if (g < 3932160) { src = wv; dst = wvh; base = 3670016; }
    else                  { src = wo; dst = woh; base = 3932160; }
    int i = g - base;
    float4 val = reinterpret_cast<const float4*>(src)[i];
    f16x4 o;
    o[0] = (f16)val.x; o[1] = (f16)val.y; o[2] = (f16)val.z; o[3] = (f16)val.w;
    reinterpret_cast<f16x4*>(dst)[i] = o;
}

// ---------------- GEMM: out[m][n] = sum_k A[m][k] * W[n][k]  (M=4096,N=1024,K=1024)
template <int OUT_F32>
__device__ __forceinline__ void gemm_body(const f16* __restrict__ A, const f16* __restrict__ W,
                                          void* __restrict__ out) {
    __shared__ __attribute__((aligned(16))) f16 Alds[128 * 32];
    __shared__ __attribute__((aligned(16))) f16 Blds[128 * 32];
    const int tid = threadIdx.x;
    const int lane = tid & 63, w = tid >> 6;
    const int g = lane >> 4, r15 = lane & 15;
    const int m0 = blockIdx.y * 128, n0 = blockIdx.x * 128;
    const int wm = (w >> 1) * 64, wn = (w & 1) * 64;

    const f32x4 zero4 = {0.f, 0.f, 0.f, 0.f};
    f32x4 acc[4][4];
#pragma unroll
    for (int i = 0; i < 4; ++i) {
#pragma unroll
        for (int j = 0; j < 4; ++j) acc[i][j] = zero4;
    }

    const int srow = w * 32 + (lane >> 2);  // + c*16
    const int sch = (lane & 3) * 8;

    for (int k0 = 0; k0 < Cd; k0 += 32) {
#pragma unroll
        for (int c = 0; c < 2; ++c) {
            int row = srow + c * 16;
            GLD_LDS16(A + (m0 + row) * Cd + k0 + sch, &Alds[(w * 2 + c) * 512]);
            GLD_LDS16(W + (n0 + row) * Cd + k0 + sch, &Blds[(w * 2 + c) * 512]);
        }
        __syncthreads();
        f16x8 af[4], bf[4];
#pragma unroll
        for (int t = 0; t < 4; ++t) {
            af[t] = *(const f16x8*)&Alds[(wm + t * 16 + r15) * 32 + g * 8];
            bf[t] = *(const f16x8*)&Blds[(wn + t * 16 + r15) * 32 + g * 8];
        }
#pragma unroll
        for (int i = 0; i < 4; ++i) {
#pragma unroll
            for (int j = 0; j < 4; ++j)
                acc[i][j] = __builtin_amdgcn_mfma_f32_16x16x32_f16(af[i], bf[j], acc[i][j], 0, 0, 0);
        }
        __syncthreads();
    }
#pragma unroll
    for (int i = 0; i < 4; ++i) {
#pragma unroll
        for (int j = 0; j < 4; ++j) {
#pragma unroll
            for (int r = 0; r < 4; ++r) {
                int row = m0 + wm + i * 16 + g * 4 + r;
                int col = n0 + wn + j * 16 + r15;
                if (OUT_F32)
                    ((float*)out)[row * Cd + col] = acc[i][j][r];
                else
                    ((f16*)out)[row * Cd + col] = (f16)acc[i][j][r];
            }
        }
    }
}

__global__ __launch_bounds__(256) void k_gemm_qkv(const f16* qh, const f16* kh, const f16* vh,
                                                  const f16* wqh, const f16* wkh, const f16* wvh,
                                                  f16* Qp, f16* Kp, f16* Vp) {
    int z = blockIdx.z;
    const f16* A = (z == 0) ? qh : (z == 1) ? kh : vh;
    const f16* W = (z == 0) ? wqh : (z == 1) ? wkh : wvh;
    f16* out = (z == 0) ? Qp : (z == 1) ? Kp : Vp;
    gemm_body<0>(A, W, out);
}

__global__ __launch_bounds__(256) void k_gemm_out(const f16* yh, const f16* woh, float* out) {
    gemm_body<1>(yh, woh, out);
}

// ---------------- RoPE in-place on Qp, Kp ----------------
__global__ void k_rope(f16* __restrict__ Qp, f16* __restrict__ Kp, const float* __restrict__ cosT,
                       const float* __restrict__ sinT) {
    int idx = blockIdx.x * 256 + threadIdx.x;  // 2 * 524288
    f16* ptr = (idx < 524288) ? Qp : Kp;
    int i = idx & 524287;
    int gi = i & 7;     // 8-elem group within head dim
    int bth = i >> 3;   // bt*16 + h
    int h = bth & 15;
    int bt = bth >> 4;
    int t = bt & 2047;
    int off = bt * 1024 + h * 64 + gi * 8;
    f16x8 v = *(f16x8*)(ptr + off);
    float4 c4 = *(const float4*)&cosT[t * 32 + gi * 4];
    float4 s4 = *(const float4*)&sinT[t * 32 + gi * 4];
    f16x8 o;
    float x0, x1;
    x0 = (float)v[0]; x1 = (float)v[1];
    o[0] = (f16)(x0 * c4.x - x1 * s4.x); o[1] = (f16)(x0 * s4.x + x1 * c4.x);
    x0 = (float)v[2]; x1 = (float)v[3];
    o[2] = (f16)(x0 * c4.y - x1 * s4.y); o[3] = (f16)(x0 * s4.y + x1 * c4.y);
    x0 = (float)v[4]; x1 = (float)v[5];
    o[4] = (f16)(x0 * c4.z - x1 * s4.z); o[5] = (f16)(x0 * s4.z + x1 * c4.z);
    x0 = (float)v[6]; x1 = (float)v[7];
    o[6] = (f16)(x0 * c4.w - x1 * s4.w); o[7] = (f16)(x0 * s4.w + x1 * c4.w);
    *(f16x8*)(ptr + off) = o;
}

// ---------------- V transpose: Vp[bt][h*64+d] -> Vt[bh][d][t] ----------------
__global__ void k_vtrans(const f16* __restrict__ Vp, f16* __restrict__ Vt) {
    __shared__ __attribute__((aligned(16))) f16 tile[64][72];
    int bh = blockIdx.y, b = bh >> 4, h = bh & 15;
    int t0 = blockIdx.x * 64;
    int tid = threadIdx.x;
#pragma unroll
    for (int c = 0; c < 2; ++c) {
        int id = c * 256 + tid;
        int row = id >> 3, ch = id & 7;
        *(f16x8*)&tile[row][ch * 8] =
            *(const f16x8*)(Vp + (b * 2048 + t0 + row) * 1024 + h * 64 + ch * 8);
    }
    __syncthreads();
#pragma unroll
    for (int c = 0; c < 2; ++c) {
        int id = c * 256 + tid;
        int d = id & 63, tch = id >> 6;  // d = lane within wave -> conflict-free LDS reads
        f16x8 vv;
#pragma unroll
        for (int j = 0; j < 8; ++j) vv[j] = tile[tch * 8 + j][d];
        *(f16x8*)(Vt + (bh * 64 + d) * 2048 + t0 + tch * 8) = vv;
    }
}

// ---------------- Flash attention: split-KV, 2 blocks/CU, counted-vmcnt pipeline ----------------
// grid: x = bh (32), y = q-block (16 x 128 rows) -> 512 blocks = 2/CU = 4 waves/SIMD.
// 8 waves: waves 0-3 (group A) process even KV tiles, 4-7 (group B) odd tiles; wave w owns
// q rows (w&3)*32..+31. Partial (m,l,o) merged through LDS at the end.
// Same-bh blocks stride 32 in linear id (32%8==0) -> same XCD -> KV stays in that XCD's L2.
// All register-array indices are compile-time constants (rule #20).
__global__ __launch_bounds__(512, 4) void k_flash(const f16* __restrict__ Qp,
                                                  const f16* __restrict__ Kp,
                                                  const f16* __restrict__ Vt,
                                                  f16* __restrict__ y) {
    __shared__ __attribute__((aligned(16))) f16 Klds[2 * 2 * 4096];  // [pairbuf][tilepar][64kv][64d]
    __shared__ __attribute__((aligned(16))) f16 Vlds[2 * 2 * 4096];  // [pairbuf][tilepar][64d][64kv]
    const int bh = blockIdx.x, b = bh >> 4, h = bh & 15;
    const int tid = threadIdx.x, lane = tid & 63, w = tid >> 6;
    const int r31 = lane & 31, hi = lane >> 5;
    const int g2 = w >> 2, qw = w & 3;

    // staging: thread t covers slot t (16B) of each of the pair's 4 tiles (K even/odd, V even/odd).
    // Global source chunk pre-XOR-swizzled (j ^ (row&7)); LDS written linearly (m173 both-sides).
    const int srow = tid >> 3, sj = tid & 7;
    const f16* gK = Kp + (b * 2048 + srow) * 1024 + h * 64 + ((sj ^ (srow & 7)) * 8);
    const f16* gV = Vt + (bh * 64 + srow) * 2048 + ((sj ^ (srow & 7)) * 8);
    f16* lK = (f16*)Klds + w * 512;  // wave-uniform base; lane writes base + lane*16B
    f16* lV = (f16*)Vlds + w * 512;

#define STAGE_PAIR(pb, pi)                                          \
    do {                                                            \
        GLD_LDS16(gK + (2 * (pi)) * 65536, lK + (pb) * 8192);       \
        GLD_LDS16(gK + (2 * (pi) + 1) * 65536, lK + (pb) * 8192 + 4096); \
        GLD_LDS16(gV + (2 * (pi)) * 64, lV + (pb) * 8192);          \
        GLD_LDS16(gV + (2 * (pi) + 1) * 64, lV + (pb) * 8192 + 4096);   \
    } while (0)

    // Q fragments (B-operand of mfma(K,Q)); 0.125 = 1/sqrt(64), log2e folds exp->exp2
    const int qrow = b * 2048 + blockIdx.y * 128 + qw * 32 + r31;
    f16x8 qf[4];
    {
        const f16* qb = Qp + qrow * 1024 + h * 64 + hi * 8;
        const f16 sc = (f16)(0.125f * 1.44269504088896f);
#pragma unroll
        for (int dc = 0; dc < 4; ++dc) {
            f16x8 v = *(const f16x8*)(qb + dc * 16);
#pragma unroll
            for (int j = 0; j < 8; ++j) v[j] = v[j] * sc;
            qf[dc] = v;
        }
    }

    f32x16 o0, o1;
#pragma unroll
    for (int r = 0; r < 16; ++r) { o0[r] = 0.f; o1[r] = 0.f; }
    float m = -1e30f, l = 0.f;

    // prologue: stage pair 0 -> buf0
    STAGE_PAIR(0, 0);

    for (int it = 0; it < 16; ++it) {
        __builtin_amdgcn_s_barrier();  // all waves done reading buf[(it+1)&1] (pair it-1)
        if (it < 15) {
            STAGE_PAIR((it + 1) & 1, it + 1);
            asm volatile("s_waitcnt vmcnt(4)" ::: "memory");  // own pair-it loads done; it+1 in flight
        } else {
            asm volatile("s_waitcnt vmcnt(0)" ::: "memory");
        }
        __builtin_amdgcn_sched_barrier(0);
        __builtin_amdgcn_s_barrier();  // everyone's pair-it stage complete
        const f16* Kb = (const f16*)Klds + (it & 1) * 8192 + g2 * 4096;
        const f16* Vb = (const f16*)Vlds + (it & 1) * 8192 + g2 * 4096;

        // S^T[kv 64][q 32] = K_tile . Q^T  (lane: col q=r31; rows (r&3)+8*(r>>2)+4*hi (+32))
        f32x16 s0, s1;
#pragma unroll
        for (int r = 0; r < 16; ++r) { s0[r] = 0.f; s1[r] = 0.f; }
        __builtin_amdgcn_s_setprio(1);
#pragma unroll
        for (int dc = 0; dc < 4; ++dc) {
            int j = (2 * dc + hi) ^ (r31 & 7);
            f16x8 k0 = *(const f16x8*)&Kb[r31 * 64 + j * 8];
            f16x8 k1 = *(const f16x8*)&Kb[(32 + r31) * 64 + j * 8];
            s0 = __builtin_amdgcn_mfma_f32_32x32x16_f16(k0, qf[dc], s0, 0, 0, 0);
            s1 = __builtin_amdgcn_mfma_f32_32x32x16_f16(k1, qf[dc], s1, 0, 0, 0);
        }
        __builtin_amdgcn_s_setprio(0);

        // online softmax (log2 domain), defer-max: skip O-rescale while growth <= 8
        float t16[16];
#pragma unroll
        for (int r = 0; r < 16; ++r) t16[r] = fmaxf(s0[r], s1[r]);
        float p0 = MAX3(t16[0], t16[1], t16[2]);
        float p1 = MAX3(t16[3], t16[4], t16[5]);
        float p2 = MAX3(t16[6], t16[7], t16[8]);
        float p3 = MAX3(t16[9], t16[10], t16[11]);
        float p4 = MAX3(t16[12], t16[13], t16[14]);
        float pmax = fmaxf(MAX3(p0, p1, p2), MAX3(p3, p4, t16[15]));
        pmax = fmaxf(pmax, __shfl_xor(pmax, 32, 64));
        if (__any(pmax > m + 8.0f)) {
            float mn = fmaxf(m, pmax);
            float cr = exp2f(m - mn);
            m = mn;
            l *= cr;
#pragma unroll
            for (int r = 0; r < 16; ++r) { o0[r] *= cr; o1[r] *= cr; }
        }
        float rs = 0.f;
#pragma unroll
        for (int r = 0; r < 16; ++r) { float p = exp2f(s0[r] - m); s0[r] = p; rs += p; }
#pragma unroll
        for (int r = 0; r < 16; ++r) { float p = exp2f(s1[r] - m); s1[r] = p; rs += p; }
        rs += __shfl_xor(rs, 32, 64);
        l += rs;

        // pack P pairs to f16; partner-exchange builds PV B-operand in-register
        unsigned pk[16], xk[16];
#pragma unroll
        for (int i = 0; i < 8; ++i) {
            auto ha = __builtin_amdgcn_cvt_pkrtz(s0[2 * i], s0[2 * i + 1]);
            __builtin_memcpy(&pk[i], &ha, 4);
            auto hb = __builtin_amdgcn_cvt_pkrtz(s1[2 * i], s1[2 * i + 1]);
            __builtin_memcpy(&pk[8 + i], &hb, 4);
        }
#pragma unroll
        for (int i = 0; i < 16; ++i) xk[i] = (unsigned)__shfl_xor((int)pk[i], 32, 64);

        // O^T[d][q] += V^T[d][kv] P[kv][q]; kv k-slices s=0..3 (16 each).
        __builtin_amdgcn_s_setprio(1);
#pragma unroll
        for (int s = 0; s < 4; ++s) {
            const int base = (s >> 1) * 8 + (s & 1) * 4;
            union { unsigned u[4]; f16x8 v; } uv;
            uv.u[0] = hi ? xk[base + 2] : pk[base + 0];
            uv.u[1] = hi ? xk[base + 3] : pk[base + 1];
            uv.u[2] = hi ? pk[base + 2] : xk[base + 0];
            uv.u[3] = hi ? pk[base + 3] : xk[base + 1];
            int j = (2 * s + hi) ^ (r31 & 7);
            f16x8 v0 = *(const f16x8*)&Vb[r31 * 64 + j * 8];
            f16x8 v1 = *(const f16x8*)&Vb[(32 + r31) * 64 + j * 8];
            o0 = __builtin_amdgcn_mfma_f32_32x32x16_f16(v0, uv.v, o0, 0, 0, 0);
            o1 = __builtin_amdgcn_mfma_f32_32x32x16_f16(v1, uv.v, o1, 0, 0, 0);
        }
        __builtin_amdgcn_s_setprio(0);
    }
#undef STAGE_PAIR

    // ---- merge group B partials into group A, then store (LDS reused, staging done) ----
    __syncthreads();
    float* Ko = (float*)Klds;  // 4 waves x 64 lanes x 32 f32 = 32 KB exactly
    float* Vm = (float*)Vlds;  // m,l pairs
    if (w >= 4) {
        const int slot = ((w - 4) * 64 + lane) * 32;
#pragma unroll
        for (int c = 0; c < 4; ++c) {
            f32x4 t;
#pragma unroll
            for (int i = 0; i < 4; ++i) t[i] = o0[c * 4 + i];
            *(f32x4*)&Ko[slot + c * 4] = t;
#pragma unroll
            for (int i = 0; i < 4; ++i) t[i] = o1[c * 4 + i];
            *(f32x4*)&Ko[slot + 16 + c * 4] = t;
        }
        Vm[((w - 4) * 64 + lane) * 2] = m;
        Vm[((w - 4) * 64 + lane) * 2 + 1] = l;
    }
    __syncthreads();
    if (w < 4) {
        const int slot = (w * 64 + lane) * 32;
        float mB = Vm[(w * 64 + lane) * 2];
        float lB = Vm[(w * 64 + lane) * 2 + 1];
        float mS = fmaxf(m, mB);
        float sA = exp2f(m - mS), sB = exp2f(mB - mS);
        float linv = 1.0f / (l * sA + lB * sB);
        sA *= linv;
        sB *= linv;
        f16* yb = y + qrow * 1024 + h * 64 + hi * 4;
#pragma unroll
        for (int rg = 0; rg < 4; ++rg) {
            f32x4 pB0 = *(const f32x4*)&Ko[slot + rg * 4];
            f32x4 pB1 = *(const f32x4*)&Ko[slot + 16 + rg * 4];
            f16x4 ov;
#pragma unroll
            for (int i = 0; i < 4; ++i) ov[i] = (f16)(o0[rg * 4 + i] * sA + pB0[i] * sB);
            *(f16x4*)&yb[rg * 8] = ov;
#pragma unroll
            for (int i = 0; i < 4; ++i) ov[i] = (f16)(o1[rg * 4 + i] * sA + pB1[i] * sB);
            *(f16x4*)&yb[32 + rg * 8] = ov;
        }
    }
}

extern "C" void kernel_launch(void* const* d_in, const int* in_sizes, int n_in, void* d_out,
                              int out_size, void* d_ws, size_t ws_size, hipStream_t stream) {
    const float* q = (const float*)d_in[0];
    const float* k = (const float*)d_in[1];
    const float* v = (const float*)d_in[2];
    const float* fr = (const float*)d_in[3];
    const float* wq = (const float*)d_in[4];
    const float* wk = (const float*)d_in[5];
    const float* wv = (const float*)d_in[6];
    const float* wo = (const float*)d_in[7];
    char* ws = (char*)d_ws;

    float* cosT = (float*)(ws + 0);
    float* sinT = (float*)(ws + 262144);
    f16* qh = (f16*)(ws + 524288);
    f16* kh = (f16*)(ws + 8912896);
    f16* vh = (f16*)(ws + 17301504);
    f16* wqh = (f16*)(ws + 25690112);
    f16* wkh = (f16*)(ws + 27787264);
    f16* wvh = (f16*)(ws + 29884416);
    f16* woh = (f16*)(ws + 31981568);
    f16* Qp = (f16*)(ws + 34078720);
    f16* Kp = (f16*)(ws + 42467328);
    f16* Vp = (f16*)(ws + 50855936);
    // qh/kh are dead after the QKV GEMM: alias Vt and y over them
    f16* Vt = (f16*)(ws + 524288);
    f16* yh = (f16*)(ws + 8912896);

    k_trig<<<256, 256, 0, stream>>>(fr, cosT, sinT);
    k_cvt<<<16384, 256, 0, stream>>>(q, k, v, wq, wk, wv, wo, qh, kh, vh, wqh, wkh, wvh, woh);
    dim3 gq(8, 32, 3);
    k_gemm_qkv<<<gq, 256, 0, stream>>>(qh, kh, vh, wqh, wkh, wvh, Qp, Kp, Vp);
    k_rope<<<4096, 256, 0, stream>>>(Qp, Kp, cosT, sinT);
    dim3 gt(32, 32);
    k_vtrans<<<gt, 256, 0, stream>>>(Vp, Vt);
    dim3 gf(32, 16);
    k_flash<<<gf, 512, 0, stream>>>(Qp, Kp, Vt, yh);
    dim3 go(8, 32);
    k_gemm_out<<<go, 256, 0, stream>>>(yh, woh, (float*)d_out);
}

// Round 6
// 169.039 us; speedup vs baseline: 1.3068x; 1.0111x over previous
//
#include <hip/hip_runtime.h>
#include <stdint.h>

#define Bd 2
#define Td 2048
#define Cd 1024
#define Hd 16
#define HDd 64
#define BT 4096

typedef _Float16 f16;
typedef __attribute__((ext_vector_type(8))) _Float16 f16x8;
typedef __attribute__((ext_vector_type(4))) _Float16 f16x4;
typedef __attribute__((ext_vector_type(2))) _Float16 f16x2;
typedef __attribute__((ext_vector_type(4))) float f32x4;
typedef __attribute__((ext_vector_type(16))) float f32x16;

#define GLD_LDS16(gptr, lptr)                                                        \
    __builtin_amdgcn_global_load_lds((const __attribute__((address_space(1))) void*)(gptr), \
                                     (__attribute__((address_space(3))) void*)(lptr), 16, 0, 0)

#define MAX3(a, b, c) fmaxf(fmaxf(a, b), c)

// ---------------- trig tables: cos/sin of freqs (T x 32) ----------------
__global__ void k_trig(const float* __restrict__ freqs, float* __restrict__ cosT,
                       float* __restrict__ sinT) {
    int i = blockIdx.x * 256 + threadIdx.x;  // 65536 total
    float f = freqs[i];
    cosT[i] = cosf(f);
    sinT[i] = sinf(f);
}

// ---------------- f32 -> f16 conversion (q,k,v,Wq,Wk,Wv,Wo) ----------------
__global__ void k_cvt(const float* __restrict__ q, const float* __restrict__ k,
                      const float* __restrict__ v, const float* __restrict__ wq,
                      const float* __restrict__ wk, const float* __restrict__ wv,
                      const float* __restrict__ wo, f16* __restrict__ qh, f16* __restrict__ kh,
                      f16* __restrict__ vh, f16* __restrict__ wqh, f16* __restrict__ wkh,
                      f16* __restrict__ wvh, f16* __restrict__ woh) {
    int g = blockIdx.x * 256 + threadIdx.x;  // float4 groups, 4194304 total
    const float* src;
    f16* dst;
    int base;
    if (g < 1048576)      { src = q;  dst = qh;  base = 0; }
    else if (g < 2097152) { src = k;  dst = kh;  base = 1048576; }
    else if (g < 3145728) { src = v;  dst = vh;  base = 2097152; }
    else if (g < 3407872) { src = wq; dst = wqh; base = 3145728; }
    else if (g < 3670016) { src = wk; dst = wkh; base = 3407872; }
    else if (g < 3932160) { src = wv; dst = wvh; base = 3670016; }
    else                  { src = wo; dst = woh; base = 3932160; }
    int i = g - base;
    float4 val = reinterpret_cast<const float4*>(src)[i];
    f16x4 o;
    o[0] = (f16)val.x; o[1] = (f16)val.y; o[2] = (f16)val.z; o[3] = (f16)val.w;
    reinterpret_cast<f16x4*>(dst)[i] = o;
}

// ---------------- GEMM: out[m][n] = sum_k A[m][k] * W[n][k]  (M=4096,N=1024,K=1024)
// BK=64, both-sides XOR-swizzled LDS (linear [128][64] would put 16 lanes/bank-quad on the
// b128 frag reads; swizzle balances to 8/quad = capacity optimum). grid x = m-tile so each
// XCD keeps one W n-panel (256KB) + its A panels hot in L2.
template <int OUT_F32>
__device__ __forceinline__ void gemm_body(const f16* __restrict__ A, const f16* __restrict__ W,
                                          void* __restrict__ out) {
    __shared__ __attribute__((aligned(16))) f16 Alds[128 * 64];
    __shared__ __attribute__((aligned(16))) f16 Blds[128 * 64];
    const int tid = threadIdx.x;
    const int lane = tid & 63, w = tid >> 6;
    const int g = lane >> 4, r15 = lane & 15;
    const int m0 = blockIdx.x * 128, n0 = blockIdx.y * 128;
    const int wm = (w >> 1) * 64, wn = (w & 1) * 64;

    const f32x4 zero4 = {0.f, 0.f, 0.f, 0.f};
    f32x4 acc[4][4];
#pragma unroll
    for (int i = 0; i < 4; ++i) {
#pragma unroll
        for (int j = 0; j < 4; ++j) acc[i][j] = zero4;
    }

    // staging: slot = c*256+tid covers 1024 x 16B slots; row = slot>>3, source chunk
    // (slot&7)^(row&7) pre-swizzled; LDS written linearly (m173 both-sides pattern).
    const int srow0 = tid >> 3;
    const int sj = tid & 7;

    for (int k0 = 0; k0 < Cd; k0 += 64) {
#pragma unroll
        for (int c = 0; c < 4; ++c) {
            int row = c * 32 + srow0;
            int ch = sj ^ (row & 7);
            GLD_LDS16(A + (m0 + row) * Cd + k0 + ch * 8, (f16*)Alds + (c * 256 + w * 64) * 8);
            GLD_LDS16(W + (n0 + row) * Cd + k0 + ch * 8, (f16*)Blds + (c * 256 + w * 64) * 8);
        }
        __syncthreads();
#pragma unroll
        for (int half = 0; half < 2; ++half) {
            f16x8 af[4], bf[4];
#pragma unroll
            for (int t = 0; t < 4; ++t) {
                int cidx = ((half << 2) | g) ^ (r15 & 7);
                af[t] = *(const f16x8*)&Alds[(wm + t * 16 + r15) * 64 + cidx * 8];
                bf[t] = *(const f16x8*)&Blds[(wn + t * 16 + r15) * 64 + cidx * 8];
            }
#pragma unroll
            for (int i = 0; i < 4; ++i) {
#pragma unroll
                for (int j = 0; j < 4; ++j)
                    acc[i][j] =
                        __builtin_amdgcn_mfma_f32_16x16x32_f16(af[i], bf[j], acc[i][j], 0, 0, 0);
            }
        }
        __syncthreads();
    }
#pragma unroll
    for (int i = 0; i < 4; ++i) {
#pragma unroll
        for (int j = 0; j < 4; ++j) {
#pragma unroll
            for (int r = 0; r < 4; ++r) {
                int row = m0 + wm + i * 16 + g * 4 + r;
                int col = n0 + wn + j * 16 + r15;
                if (OUT_F32)
                    ((float*)out)[row * Cd + col] = acc[i][j][r];
                else
                    ((f16*)out)[row * Cd + col] = (f16)acc[i][j][r];
            }
        }
    }
}

__global__ __launch_bounds__(256) void k_gemm_qkv(const f16* qh, const f16* kh, const f16* vh,
                                                  const f16* wqh, const f16* wkh, const f16* wvh,
                                                  f16* Qp, f16* Kp, f16* Vp) {
    int z = blockIdx.z;
    const f16* A = (z == 0) ? qh : (z == 1) ? kh : vh;
    const f16* W = (z == 0) ? wqh : (z == 1) ? wkh : wvh;
    f16* out = (z == 0) ? Qp : (z == 1) ? Kp : Vp;
    gemm_body<0>(A, W, out);
}

__global__ __launch_bounds__(256) void k_gemm_out(const f16* yh, const f16* woh, float* out) {
    gemm_body<1>(yh, woh, out);
}

// ---------------- RoPE in-place on Qp, Kp ----------------
__global__ void k_rope(f16* __restrict__ Qp, f16* __restrict__ Kp, const float* __restrict__ cosT,
                       const float* __restrict__ sinT) {
    int idx = blockIdx.x * 256 + threadIdx.x;  // 2 * 524288
    f16* ptr = (idx < 524288) ? Qp : Kp;
    int i = idx & 524287;
    int gi = i & 7;     // 8-elem group within head dim
    int bth = i >> 3;   // bt*16 + h
    int h = bth & 15;
    int bt = bth >> 4;
    int t = bt & 2047;
    int off = bt * 1024 + h * 64 + gi * 8;
    f16x8 v = *(f16x8*)(ptr + off);
    float4 c4 = *(const float4*)&cosT[t * 32 + gi * 4];
    float4 s4 = *(const float4*)&sinT[t * 32 + gi * 4];
    f16x8 o;
    float x0, x1;
    x0 = (float)v[0]; x1 = (float)v[1];
    o[0] = (f16)(x0 * c4.x - x1 * s4.x); o[1] = (f16)(x0 * s4.x + x1 * c4.x);
    x0 = (float)v[2]; x1 = (float)v[3];
    o[2] = (f16)(x0 * c4.y - x1 * s4.y); o[3] = (f16)(x0 * s4.y + x1 * c4.y);
    x0 = (float)v[4]; x1 = (float)v[5];
    o[4] = (f16)(x0 * c4.z - x1 * s4.z); o[5] = (f16)(x0 * s4.z + x1 * c4.z);
    x0 = (float)v[6]; x1 = (float)v[7];
    o[6] = (f16)(x0 * c4.w - x1 * s4.w); o[7] = (f16)(x0 * s4.w + x1 * c4.w);
    *(f16x8*)(ptr + off) = o;
}

// ---------------- V transpose: Vp[bt][h*64+d] -> Vt[bh][d][t] ----------------
__global__ void k_vtrans(const f16* __restrict__ Vp, f16* __restrict__ Vt) {
    __shared__ __attribute__((aligned(16))) f16 tile[64][72];
    int bh = blockIdx.y, b = bh >> 4, h = bh & 15;
    int t0 = blockIdx.x * 64;
    int tid = threadIdx.x;
#pragma unroll
    for (int c = 0; c < 2; ++c) {
        int id = c * 256 + tid;
        int row = id >> 3, ch = id & 7;
        *(f16x8*)&tile[row][ch * 8] =
            *(const f16x8*)(Vp + (b * 2048 + t0 + row) * 1024 + h * 64 + ch * 8);
    }
    __syncthreads();
#pragma unroll
    for (int c = 0; c < 2; ++c) {
        int id = c * 256 + tid;
        int d = id & 63, tch = id >> 6;  // d = lane within wave -> conflict-free LDS reads
        f16x8 vv;
#pragma unroll
        for (int j = 0; j < 8; ++j) vv[j] = tile[tch * 8 + j][d];
        *(f16x8*)(Vt + (bh * 64 + d) * 2048 + t0 + tch * 8) = vv;
    }
}

// ---------------- Flash attention: split-KV, 2 blocks/CU, counted-vmcnt pipeline ----------------
// grid: x = bh (32), y = q-block (16 x 128 rows) -> 512 blocks = 2/CU = 4 waves/SIMD.
// Waves 0-3 even KV tiles, 4-7 odd tiles; merge partials via LDS at the end.
// Critical-path edits vs R5: rs tree-reduce (depth 5 vs 32 serial adds), and the rs cross-half
// shuffle + l update moved AFTER the PV MFMAs (l unused until next tile's rescale).
// All register-array indices compile-time constant (rule #20).
__global__ __launch_bounds__(512, 4) void k_flash(const f16* __restrict__ Qp,
                                                  const f16* __restrict__ Kp,
                                                  const f16* __restrict__ Vt,
                                                  f16* __restrict__ y) {
    __shared__ __attribute__((aligned(16))) f16 Klds[2 * 2 * 4096];  // [pairbuf][tilepar][64kv][64d]
    __shared__ __attribute__((aligned(16))) f16 Vlds[2 * 2 * 4096];  // [pairbuf][tilepar][64d][64kv]
    const int bh = blockIdx.x, b = bh >> 4, h = bh & 15;
    const int tid = threadIdx.x, lane = tid & 63, w = tid >> 6;
    const int r31 = lane & 31, hi = lane >> 5;
    const int g2 = w >> 2, qw = w & 3;

    const int srow = tid >> 3, sj = tid & 7;
    const f16* gK = Kp + (b * 2048 + srow) * 1024 + h * 64 + ((sj ^ (srow & 7)) * 8);
    const f16* gV = Vt + (bh * 64 + srow) * 2048 + ((sj ^ (srow & 7)) * 8);
    f16* lK = (f16*)Klds + w * 512;  // wave-uniform base; lane writes base + lane*16B
    f16* lV = (f16*)Vlds + w * 512;

#define STAGE_PAIR(pb, pi)                                          \
    do {                                                            \
        GLD_LDS16(gK + (2 * (pi)) * 65536, lK + (pb) * 8192);       \
        GLD_LDS16(gK + (2 * (pi) + 1) * 65536, lK + (pb) * 8192 + 4096); \
        GLD_LDS16(gV + (2 * (pi)) * 64, lV + (pb) * 8192);          \
        GLD_LDS16(gV + (2 * (pi) + 1) * 64, lV + (pb) * 8192 + 4096);   \
    } while (0)

    // Q fragments (B-operand of mfma(K,Q)); 0.125 = 1/sqrt(64), log2e folds exp->exp2
    const int qrow = b * 2048 + blockIdx.y * 128 + qw * 32 + r31;
    f16x8 qf[4];
    {
        const f16* qb = Qp + qrow * 1024 + h * 64 + hi * 8;
        const f16 sc = (f16)(0.125f * 1.44269504088896f);
#pragma unroll
        for (int dc = 0; dc < 4; ++dc) {
            f16x8 v = *(const f16x8*)(qb + dc * 16);
#pragma unroll
            for (int j = 0; j < 8; ++j) v[j] = v[j] * sc;
            qf[dc] = v;
        }
    }

    f32x16 o0, o1;
#pragma unroll
    for (int r = 0; r < 16; ++r) { o0[r] = 0.f; o1[r] = 0.f; }
    float m = -1e30f, l = 0.f;

    STAGE_PAIR(0, 0);

    for (int it = 0; it < 16; ++it) {
        __builtin_amdgcn_s_barrier();  // all waves done reading buf[(it+1)&1] (pair it-1)
        if (it < 15) {
            STAGE_PAIR((it + 1) & 1, it + 1);
            asm volatile("s_waitcnt vmcnt(4)" ::: "memory");  // own pair-it loads done; it+1 in flight
        } else {
            asm volatile("s_waitcnt vmcnt(0)" ::: "memory");
        }
        __builtin_amdgcn_sched_barrier(0);
        __builtin_amdgcn_s_barrier();  // everyone's pair-it stage complete
        const f16* Kb = (const f16*)Klds + (it & 1) * 8192 + g2 * 4096;
        const f16* Vb = (const f16*)Vlds + (it & 1) * 8192 + g2 * 4096;

        // S^T[kv 64][q 32] = K_tile . Q^T  (lane: col q=r31; rows (r&3)+8*(r>>2)+4*hi (+32))
        f32x16 s0, s1;
#pragma unroll
        for (int r = 0; r < 16; ++r) { s0[r] = 0.f; s1[r] = 0.f; }
        __builtin_amdgcn_s_setprio(1);
#pragma unroll
        for (int dc = 0; dc < 4; ++dc) {
            int j = (2 * dc + hi) ^ (r31 & 7);
            f16x8 k0 = *(const f16x8*)&Kb[r31 * 64 + j * 8];
            f16x8 k1 = *(const f16x8*)&Kb[(32 + r31) * 64 + j * 8];
            s0 = __builtin_amdgcn_mfma_f32_32x32x16_f16(k0, qf[dc], s0, 0, 0, 0);
            s1 = __builtin_amdgcn_mfma_f32_32x32x16_f16(k1, qf[dc], s1, 0, 0, 0);
        }
        __builtin_amdgcn_s_setprio(0);

        // online softmax (log2 domain), defer-max: skip O-rescale while growth <= 8
        float t16[16];
#pragma unroll
        for (int r = 0; r < 16; ++r) t16[r] = fmaxf(s0[r], s1[r]);
        float p0 = MAX3(t16[0], t16[1], t16[2]);
        float p1 = MAX3(t16[3], t16[4], t16[5]);
        float p2 = MAX3(t16[6], t16[7], t16[8]);
        float p3 = MAX3(t16[9], t16[10], t16[11]);
        float p4 = MAX3(t16[12], t16[13], t16[14]);
        float pmax = fmaxf(MAX3(p0, p1, p2), MAX3(p3, p4, t16[15]));
        pmax = fmaxf(pmax, __shfl_xor(pmax, 32, 64));
        if (__any(pmax > m + 8.0f)) {
            float mn = fmaxf(m, pmax);
            float cr = exp2f(m - mn);
            m = mn;
            l *= cr;
#pragma unroll
            for (int r = 0; r < 16; ++r) { o0[r] *= cr; o1[r] *= cr; }
        }
#pragma unroll
        for (int r = 0; r < 16; ++r) s0[r] = exp2f(s0[r] - m);
#pragma unroll
        for (int r = 0; r < 16; ++r) s1[r] = exp2f(s1[r] - m);
        // tree-reduce row sum (depth 5, off the critical path vs 32 serial adds)
        float a16[16];
#pragma unroll
        for (int r = 0; r < 16; ++r) a16[r] = s0[r] + s1[r];
#pragma unroll
        for (int r = 0; r < 8; ++r) a16[r] += a16[r + 8];
#pragma unroll
        for (int r = 0; r < 4; ++r) a16[r] += a16[r + 4];
        float rs = (a16[0] + a16[1]) + (a16[2] + a16[3]);

        // pack P pairs to f16; partner-exchange builds PV B-operand in-register
        unsigned pk[16], xk[16];
#pragma unroll
        for (int i = 0; i < 8; ++i) {
            auto ha = __builtin_amdgcn_cvt_pkrtz(s0[2 * i], s0[2 * i + 1]);
            __builtin_memcpy(&pk[i], &ha, 4);
            auto hb = __builtin_amdgcn_cvt_pkrtz(s1[2 * i], s1[2 * i + 1]);
            __builtin_memcpy(&pk[8 + i], &hb, 4);
        }
#pragma unroll
        for (int i = 0; i < 16; ++i) xk[i] = (unsigned)__shfl_xor((int)pk[i], 32, 64);

        // O^T[d][q] += V^T[d][kv] P[kv][q]; kv k-slices s=0..3 (16 each).
        __builtin_amdgcn_s_setprio(1);
#pragma unroll
        for (int s = 0; s < 4; ++s) {
            const int base = (s >> 1) * 8 + (s & 1) * 4;
            union { unsigned u[4]; f16x8 v; } uv;
            uv.u[0] = hi ? xk[base + 2] : pk[base + 0];
            uv.u[1] = hi ? xk[base + 3] : pk[base + 1];
            uv.u[2] = hi ? pk[base + 2] : xk[base + 0];
            uv.u[3] = hi ? pk[base + 3] : xk[base + 1];
            int j = (2 * s + hi) ^ (r31 & 7);
            f16x8 v0 = *(const f16x8*)&Vb[r31 * 64 + j * 8];
            f16x8 v1 = *(const f16x8*)&Vb[(32 + r31) * 64 + j * 8];
            o0 = __builtin_amdgcn_mfma_f32_32x32x16_f16(v0, uv.v, o0, 0, 0, 0);
            o1 = __builtin_amdgcn_mfma_f32_32x32x16_f16(v1, uv.v, o1, 0, 0, 0);
        }
        __builtin_amdgcn_s_setprio(0);

        // l update off the critical path: shfl latency hides under the PV MFMAs above
        rs += __shfl_xor(rs, 32, 64);
        l += rs;
    }
#undef STAGE_PAIR

    // ---- merge group B partials into group A, then store (LDS reused, staging done) ----
    __syncthreads();
    float* Ko = (float*)Klds;  // 4 waves x 64 lanes x 32 f32 = 32 KB exactly
    float* Vm = (float*)Vlds;  // m,l pairs
    if (w >= 4) {
        const int slot = ((w - 4) * 64 + lane) * 32;
#pragma unroll
        for (int c = 0; c < 4; ++c) {
            f32x4 t;
#pragma unroll
            for (int i = 0; i < 4; ++i) t[i] = o0[c * 4 + i];
            *(f32x4*)&Ko[slot + c * 4] = t;
#pragma unroll
            for (int i = 0; i < 4; ++i) t[i] = o1[c * 4 + i];
            *(f32x4*)&Ko[slot + 16 + c * 4] = t;
        }
        Vm[((w - 4) * 64 + lane) * 2] = m;
        Vm[((w - 4) * 64 + lane) * 2 + 1] = l;
    }
    __syncthreads();
    if (w < 4) {
        const int slot = (w * 64 + lane) * 32;
        float mB = Vm[(w * 64 + lane) * 2];
        float lB = Vm[(w * 64 + lane) * 2 + 1];
        float mS = fmaxf(m, mB);
        float sA = exp2f(m - mS), sB = exp2f(mB - mS);
        float linv = 1.0f / (l * sA + lB * sB);
        sA *= linv;
        sB *= linv;
        f16* yb = y + qrow * 1024 + h * 64 + hi * 4;
#pragma unroll
        for (int rg = 0; rg < 4; ++rg) {
            f32x4 pB0 = *(const f32x4*)&Ko[slot + rg * 4];
            f32x4 pB1 = *(const f32x4*)&Ko[slot + 16 + rg * 4];
            f16x4 ov;
#pragma unroll
            for (int i = 0; i < 4; ++i) ov[i] = (f16)(o0[rg * 4 + i] * sA + pB0[i] * sB);
            *(f16x4*)&yb[rg * 8] = ov;
#pragma unroll
            for (int i = 0; i < 4; ++i) ov[i] = (f16)(o1[rg * 4 + i] * sA + pB1[i] * sB);
            *(f16x4*)&yb[32 + rg * 8] = ov;
        }
    }
}

extern "C" void kernel_launch(void* const* d_in, const int* in_sizes, int n_in, void* d_out,
                              int out_size, void* d_ws, size_t ws_size, hipStream_t stream) {
    const float* q = (const float*)d_in[0];
    const float* k = (const float*)d_in[1];
    const float* v = (const float*)d_in[2];
    const float* fr = (const float*)d_in[3];
    const float* wq = (const float*)d_in[4];
    const float* wk = (const float*)d_in[5];
    const float* wv = (const float*)d_in[6];
    const float* wo = (const float*)d_in[7];
    char* ws = (char*)d_ws;

    float* cosT = (float*)(ws + 0);
    float* sinT = (float*)(ws + 262144);
    f16* qh = (f16*)(ws + 524288);
    f16* kh = (f16*)(ws + 8912896);
    f16* vh = (f16*)(ws + 17301504);
    f16* wqh = (f16*)(ws + 25690112);
    f16* wkh = (f16*)(ws + 27787264);
    f16* wvh = (f16*)(ws + 29884416);
    f16* woh = (f16*)(ws + 31981568);
    f16* Qp = (f16*)(ws + 34078720);
    f16* Kp = (f16*)(ws + 42467328);
    f16* Vp = (f16*)(ws + 50855936);
    // qh/kh are dead after the QKV GEMM: alias Vt and y over them
    f16* Vt = (f16*)(ws + 524288);
    f16* yh = (f16*)(ws + 8912896);

    k_trig<<<256, 256, 0, stream>>>(fr, cosT, sinT);
    k_cvt<<<16384, 256, 0, stream>>>(q, k, v, wq, wk, wv, wo, qh, kh, vh, wqh, wkh, wvh, woh);
    dim3 gq(32, 8, 3);
    k_gemm_qkv<<<gq, 256, 0, stream>>>(qh, kh, vh, wqh, wkh, wvh, Qp, Kp, Vp);
    k_rope<<<4096, 256, 0, stream>>>(Qp, Kp, cosT, sinT);
    dim3 gt(32, 32);
    k_vtrans<<<gt, 256, 0, stream>>>(Vp, Vt);
    dim3 gf(32, 16);
    k_flash<<<gf, 512, 0, stream>>>(Qp, Kp, Vt, yh);
    dim3 go(32, 8);
    k_gemm_out<<<go, 256, 0, stream>>>(yh, woh, (float*)d_out);
}

// Round 9
// 165.294 us; speedup vs baseline: 1.3364x; 1.0227x over previous
//
#include <hip/hip_runtime.h>
#include <stdint.h>

#define Bd 2
#define Td 2048
#define Cd 1024
#define Hd 16
#define HDd 64
#define BT 4096

typedef _Float16 f16;
typedef __attribute__((ext_vector_type(8))) _Float16 f16x8;
typedef __attribute__((ext_vector_type(4))) _Float16 f16x4;
typedef __attribute__((ext_vector_type(2))) _Float16 f16x2;
typedef __attribute__((ext_vector_type(4))) float f32x4;
typedef __attribute__((ext_vector_type(16))) float f32x16;
typedef __attribute__((ext_vector_type(2))) unsigned uint2v;

#define GLD_LDS16(gptr, lptr)                                                        \
    __builtin_amdgcn_global_load_lds((const __attribute__((address_space(1))) void*)(gptr), \
                                     (__attribute__((address_space(3))) void*)(lptr), 16, 0, 0)

#define MAX3(a, b, c) fmaxf(fmaxf(a, b), c)

// cross-half (lane i <-> lane i^32) value pair via permlane32_swap intrinsic.
// SSA form: backend inserts the register copy; no aliasing hazard (R7 lesson:
// two "+v" asm operands holding the SAME value got coalesced into one VGPR,
// turning the swap into an in-place rotation -> silent softmax corruption).
// NOTE: ext_vector elements can't have their address taken -> copy by value first.
__device__ __forceinline__ float2 xhalf_pair(float v) {
    uint2v r = __builtin_amdgcn_permlane32_swap(__float_as_uint(v), __float_as_uint(v), false, false);
    unsigned lo = r[0], hi = r[1];
    float2 out;
    out.x = __uint_as_float(lo);
    out.y = __uint_as_float(hi);
    return out;  // lane i<32: {own, partner}; lane i>=32: {partner, own}
}

// ---------------- trig tables: cos/sin of freqs (T x 32) ----------------
__global__ void k_trig(const float* __restrict__ freqs, float* __restrict__ cosT,
                       float* __restrict__ sinT) {
    int i = blockIdx.x * 256 + threadIdx.x;  // 65536 total
    float f = freqs[i];
    cosT[i] = cosf(f);
    sinT[i] = sinf(f);
}

// ---------------- f32 -> f16 conversion (q,k,v,Wq,Wk,Wv,Wo) ----------------
__global__ void k_cvt(const float* __restrict__ q, const float* __restrict__ k,
                      const float* __restrict__ v, const float* __restrict__ wq,
                      const float* __restrict__ wk, const float* __restrict__ wv,
                      const float* __restrict__ wo, f16* __restrict__ qh, f16* __restrict__ kh,
                      f16* __restrict__ vh, f16* __restrict__ wqh, f16* __restrict__ wkh,
                      f16* __restrict__ wvh, f16* __restrict__ woh) {
    int g = blockIdx.x * 256 + threadIdx.x;  // float4 groups, 4194304 total
    const float* src;
    f16* dst;
    int base;
    if (g < 1048576)      { src = q;  dst = qh;  base = 0; }
    else if (g < 2097152) { src = k;  dst = kh;  base = 1048576; }
    else if (g < 3145728) { src = v;  dst = vh;  base = 2097152; }
    else if (g < 3407872) { src = wq; dst = wqh; base = 3145728; }
    else if (g < 3670016) { src = wk; dst = wkh; base = 3407872; }
    else if (g < 3932160) { src = wv; dst = wvh; base = 3670016; }
    else                  { src = wo; dst = woh; base = 3932160; }
    int i = g - base;
    float4 val = reinterpret_cast<const float4*>(src)[i];
    f16x4 o;
    o[0] = (f16)val.x; o[1] = (f16)val.y; o[2] = (f16)val.z; o[3] = (f16)val.w;
    reinterpret_cast<f16x4*>(dst)[i] = o;
}

// ---------------- GEMM: out[m][n] = sum_k A[m][k] * W[n][k]  (M=4096,N=1024,K=1024)
// BK=64, both-sides XOR-swizzled LDS. grid x = m-tile so each XCD keeps one W n-panel hot in L2.
template <int OUT_F32>
__device__ __forceinline__ void gemm_body(const f16* __restrict__ A, const f16* __restrict__ W,
                                          void* __restrict__ out) {
    __shared__ __attribute__((aligned(16))) f16 Alds[128 * 64];
    __shared__ __attribute__((aligned(16))) f16 Blds[128 * 64];
    const int tid = threadIdx.x;
    const int lane = tid & 63, w = tid >> 6;
    const int g = lane >> 4, r15 = lane & 15;
    const int m0 = blockIdx.x * 128, n0 = blockIdx.y * 128;
    const int wm = (w >> 1) * 64, wn = (w & 1) * 64;

    const f32x4 zero4 = {0.f, 0.f, 0.f, 0.f};
    f32x4 acc[4][4];
#pragma unroll
    for (int i = 0; i < 4; ++i) {
#pragma unroll
        for (int j = 0; j < 4; ++j) acc[i][j] = zero4;
    }

    const int srow0 = tid >> 3;
    const int sj = tid & 7;

    for (int k0 = 0; k0 < Cd; k0 += 64) {
#pragma unroll
        for (int c = 0; c < 4; ++c) {
            int row = c * 32 + srow0;
            int ch = sj ^ (row & 7);
            GLD_LDS16(A + (m0 + row) * Cd + k0 + ch * 8, (f16*)Alds + (c * 256 + w * 64) * 8);
            GLD_LDS16(W + (n0 + row) * Cd + k0 + ch * 8, (f16*)Blds + (c * 256 + w * 64) * 8);
        }
        __syncthreads();
#pragma unroll
        for (int half = 0; half < 2; ++half) {
            f16x8 af[4], bf[4];
#pragma unroll
            for (int t = 0; t < 4; ++t) {
                int cidx = ((half << 2) | g) ^ (r15 & 7);
                af[t] = *(const f16x8*)&Alds[(wm + t * 16 + r15) * 64 + cidx * 8];
                bf[t] = *(const f16x8*)&Blds[(wn + t * 16 + r15) * 64 + cidx * 8];
            }
#pragma unroll
            for (int i = 0; i < 4; ++i) {
#pragma unroll
                for (int j = 0; j < 4; ++j)
                    acc[i][j] =
                        __builtin_amdgcn_mfma_f32_16x16x32_f16(af[i], bf[j], acc[i][j], 0, 0, 0);
            }
        }
        __syncthreads();
    }
#pragma unroll
    for (int i = 0; i < 4; ++i) {
#pragma unroll
        for (int j = 0; j < 4; ++j) {
#pragma unroll
            for (int r = 0; r < 4; ++r) {
                int row = m0 + wm + i * 16 + g * 4 + r;
                int col = n0 + wn + j * 16 + r15;
                if (OUT_F32)
                    ((float*)out)[row * Cd + col] = acc[i][j][r];
                else
                    ((f16*)out)[row * Cd + col] = (f16)acc[i][j][r];
            }
        }
    }
}

__global__ __launch_bounds__(256) void k_gemm_qkv(const f16* qh, const f16* kh, const f16* vh,
                                                  const f16* wqh, const f16* wkh, const f16* wvh,
                                                  f16* Qp, f16* Kp, f16* Vp) {
    int z = blockIdx.z;
    const f16* A = (z == 0) ? qh : (z == 1) ? kh : vh;
    const f16* W = (z == 0) ? wqh : (z == 1) ? wkh : wvh;
    f16* out = (z == 0) ? Qp : (z == 1) ? Kp : Vp;
    gemm_body<0>(A, W, out);
}

__global__ __launch_bounds__(256) void k_gemm_out(const f16* yh, const f16* woh, float* out) {
    gemm_body<1>(yh, woh, out);
}

// ---------------- RoPE in-place on Qp, Kp ----------------
__global__ void k_rope(f16* __restrict__ Qp, f16* __restrict__ Kp, const float* __restrict__ cosT,
                       const float* __restrict__ sinT) {
    int idx = blockIdx.x * 256 + threadIdx.x;  // 2 * 524288
    f16* ptr = (idx < 524288) ? Qp : Kp;
    int i = idx & 524287;
    int gi = i & 7;     // 8-elem group within head dim
    int bth = i >> 3;   // bt*16 + h
    int h = bth & 15;
    int bt = bth >> 4;
    int t = bt & 2047;
    int off = bt * 1024 + h * 64 + gi * 8;
    f16x8 v = *(f16x8*)(ptr + off);
    float4 c4 = *(const float4*)&cosT[t * 32 + gi * 4];
    float4 s4 = *(const float4*)&sinT[t * 32 + gi * 4];
    f16x8 o;
    float x0, x1;
    x0 = (float)v[0]; x1 = (float)v[1];
    o[0] = (f16)(x0 * c4.x - x1 * s4.x); o[1] = (f16)(x0 * s4.x + x1 * c4.x);
    x0 = (float)v[2]; x1 = (float)v[3];
    o[2] = (f16)(x0 * c4.y - x1 * s4.y); o[3] = (f16)(x0 * s4.y + x1 * c4.y);
    x0 = (float)v[4]; x1 = (float)v[5];
    o[4] = (f16)(x0 * c4.z - x1 * s4.z); o[5] = (f16)(x0 * s4.z + x1 * c4.z);
    x0 = (float)v[6]; x1 = (float)v[7];
    o[6] = (f16)(x0 * c4.w - x1 * s4.w); o[7] = (f16)(x0 * s4.w + x1 * c4.w);
    *(f16x8*)(ptr + off) = o;
}

// ---------------- V transpose: Vp[bt][h*64+d] -> Vt[bh][d][t] ----------------
__global__ void k_vtrans(const f16* __restrict__ Vp, f16* __restrict__ Vt) {
    __shared__ __attribute__((aligned(16))) f16 tile[64][72];
    int bh = blockIdx.y, b = bh >> 4, h = bh & 15;
    int t0 = blockIdx.x * 64;
    int tid = threadIdx.x;
#pragma unroll
    for (int c = 0; c < 2; ++c) {
        int id = c * 256 + tid;
        int row = id >> 3, ch = id & 7;
        *(f16x8*)&tile[row][ch * 8] =
            *(const f16x8*)(Vp + (b * 2048 + t0 + row) * 1024 + h * 64 + ch * 8);
    }
    __syncthreads();
#pragma unroll
    for (int c = 0; c < 2; ++c) {
        int id = c * 256 + tid;
        int d = id & 63, tch = id >> 6;  // d = lane within wave -> conflict-free LDS reads
        f16x8 vv;
#pragma unroll
        for (int j = 0; j < 8; ++j) vv[j] = tile[tch * 8 + j][d];
        *(f16x8*)(Vt + (bh * 64 + d) * 2048 + t0 + tch * 8) = vv;
    }
}

// ---------------- Flash attention: split-KV, 2 blocks/CU, counted-vmcnt pipeline ----------------
// grid: x = bh (32), y = q-block (16 x 128 rows) -> 512 blocks = 2/CU = 4 waves/SIMD.
// Waves 0-3 even KV tiles, 4-7 odd; merge partials via LDS at the end.
// T12 permlane32_swap (via intrinsic) for: PV B-operand cross-half exchange (8 swaps replace
// 16 ds_bpermute + 16 cndmask) and pmax/rs cross-half reductions (~4cy vs ~120cy bpermute).
// All register-array indices compile-time constant (rule #20).
__global__ __launch_bounds__(512, 4) void k_flash(const f16* __restrict__ Qp,
                                                  const f16* __restrict__ Kp,
                                                  const f16* __restrict__ Vt,
                                                  f16* __restrict__ y) {
    __shared__ __attribute__((aligned(16))) f16 Klds[2 * 2 * 4096];  // [pairbuf][tilepar][64kv][64d]
    __shared__ __attribute__((aligned(16))) f16 Vlds[2 * 2 * 4096];  // [pairbuf][tilepar][64d][64kv]
    const int bh = blockIdx.x, b = bh >> 4, h = bh & 15;
    const int tid = threadIdx.x, lane = tid & 63, w = tid >> 6;
    const int r31 = lane & 31, hi = lane >> 5;
    const int g2 = w >> 2, qw = w & 3;

    const int srow = tid >> 3, sj = tid & 7;
    const f16* gK = Kp + (b * 2048 + srow) * 1024 + h * 64 + ((sj ^ (srow & 7)) * 8);
    const f16* gV = Vt + (bh * 64 + srow) * 2048 + ((sj ^ (srow & 7)) * 8);
    f16* lK = (f16*)Klds + w * 512;  // wave-uniform base; lane writes base + lane*16B
    f16* lV = (f16*)Vlds + w * 512;

#define STAGE_PAIR(pb, pi)                                          \
    do {                                                            \
        GLD_LDS16(gK + (2 * (pi)) * 65536, lK + (pb) * 8192);       \
        GLD_LDS16(gK + (2 * (pi) + 1) * 65536, lK + (pb) * 8192 + 4096); \
        GLD_LDS16(gV + (2 * (pi)) * 64, lV + (pb) * 8192);          \
        GLD_LDS16(gV + (2 * (pi) + 1) * 64, lV + (pb) * 8192 + 4096);   \
    } while (0)

    // Q fragments (B-operand of mfma(K,Q)); 0.125 = 1/sqrt(64), log2e folds exp->exp2
    const int qrow = b * 2048 + blockIdx.y * 128 + qw * 32 + r31;
    f16x8 qf[4];
    {
        const f16* qb = Qp + qrow * 1024 + h * 64 + hi * 8;
        const f16 sc = (f16)(0.125f * 1.44269504088896f);
#pragma unroll
        for (int dc = 0; dc < 4; ++dc) {
            f16x8 v = *(const f16x8*)(qb + dc * 16);
#pragma unroll
            for (int j = 0; j < 8; ++j) v[j] = v[j] * sc;
            qf[dc] = v;
        }
    }

    f32x16 o0, o1;
#pragma unroll
    for (int r = 0; r < 16; ++r) { o0[r] = 0.f; o1[r] = 0.f; }
    float m = -1e30f, l = 0.f;

    STAGE_PAIR(0, 0);

    for (int it = 0; it < 16; ++it) {
        __builtin_amdgcn_s_barrier();  // all waves done reading buf[(it+1)&1] (pair it-1)
        if (it < 15) {
            STAGE_PAIR((it + 1) & 1, it + 1);
            asm volatile("s_waitcnt vmcnt(4)" ::: "memory");  // own pair-it loads done; it+1 in flight
        } else {
            asm volatile("s_waitcnt vmcnt(0)" ::: "memory");
        }
        __builtin_amdgcn_sched_barrier(0);
        __builtin_amdgcn_s_barrier();  // everyone's pair-it stage complete
        const f16* Kb = (const f16*)Klds + (it & 1) * 8192 + g2 * 4096;
        const f16* Vb = (const f16*)Vlds + (it & 1) * 8192 + g2 * 4096;

        // S^T[kv 64][q 32] = K_tile . Q^T  (lane: col q=r31; rows (r&3)+8*(r>>2)+4*hi (+32))
        f32x16 s0, s1;
#pragma unroll
        for (int r = 0; r < 16; ++r) { s0[r] = 0.f; s1[r] = 0.f; }
        __builtin_amdgcn_s_setprio(1);
#pragma unroll
        for (int dc = 0; dc < 4; ++dc) {
            int j = (2 * dc + hi) ^ (r31 & 7);
            f16x8 k0 = *(const f16x8*)&Kb[r31 * 64 + j * 8];
            f16x8 k1 = *(const f16x8*)&Kb[(32 + r31) * 64 + j * 8];
            s0 = __builtin_amdgcn_mfma_f32_32x32x16_f16(k0, qf[dc], s0, 0, 0, 0);
            s1 = __builtin_amdgcn_mfma_f32_32x32x16_f16(k1, qf[dc], s1, 0, 0, 0);
        }
        __builtin_amdgcn_s_setprio(0);

        // online softmax (log2 domain), defer-max: skip O-rescale while growth <= 8
        float t16[16];
#pragma unroll
        for (int r = 0; r < 16; ++r) t16[r] = fmaxf(s0[r], s1[r]);
        float p0 = MAX3(t16[0], t16[1], t16[2]);
        float p1 = MAX3(t16[3], t16[4], t16[5]);
        float p2 = MAX3(t16[6], t16[7], t16[8]);
        float p3 = MAX3(t16[9], t16[10], t16[11]);
        float p4 = MAX3(t16[12], t16[13], t16[14]);
        float pmax = fmaxf(MAX3(p0, p1, p2), MAX3(p3, p4, t16[15]));
        {
            float2 pm = xhalf_pair(pmax);  // cross-half max via permlane intrinsic
            pmax = fmaxf(pm.x, pm.y);
        }
        if (__any(pmax > m + 8.0f)) {
            float mn = fmaxf(m, pmax);
            float cr = exp2f(m - mn);
            m = mn;
            l *= cr;
#pragma unroll
            for (int r = 0; r < 16; ++r) { o0[r] *= cr; o1[r] *= cr; }
        }
#pragma unroll
        for (int r = 0; r < 16; ++r) s0[r] = exp2f(s0[r] - m);
#pragma unroll
        for (int r = 0; r < 16; ++r) s1[r] = exp2f(s1[r] - m);
        // tree-reduce row sum (depth 5)
        float a16[16];
#pragma unroll
        for (int r = 0; r < 16; ++r) a16[r] = s0[r] + s1[r];
#pragma unroll
        for (int r = 0; r < 8; ++r) a16[r] += a16[r + 8];
#pragma unroll
        for (int r = 0; r < 4; ++r) a16[r] += a16[r + 4];
        float rs = (a16[0] + a16[1]) + (a16[2] + a16[3]);

        // pack P pairs to f16 (pk[i] = rows {2i,2i+1} of this lane's kv set)
        unsigned pk[16];
#pragma unroll
        for (int i = 0; i < 8; ++i) {
            auto ha = __builtin_amdgcn_cvt_pkrtz(s0[2 * i], s0[2 * i + 1]);
            __builtin_memcpy(&pk[i], &ha, 4);
            auto hb = __builtin_amdgcn_cvt_pkrtz(s1[2 * i], s1[2 * i + 1]);
            __builtin_memcpy(&pk[8 + i], &hb, 4);
        }

        // O^T[d][q] += V^T[d][kv] P[kv][q]; kv k-slices s=0..3 (16 each).
        // permlane32_swap(old=pk[b+0], src=pk[b+2]) -> r[0] = {own b+0 | partner b+2} = u[0],
        // r[1] = {partner b+0 | own b+2} = u[2]  (verified vs R6's ternary mapping).
        __builtin_amdgcn_s_setprio(1);
#pragma unroll
        for (int s = 0; s < 4; ++s) {
            const int base = (s >> 1) * 8 + (s & 1) * 4;
            uint2v r0 = __builtin_amdgcn_permlane32_swap(pk[base + 0], pk[base + 2], false, false);
            uint2v r1 = __builtin_amdgcn_permlane32_swap(pk[base + 1], pk[base + 3], false, false);
            union { unsigned u[4]; f16x8 v; } uv;
            uv.u[0] = r0[0];
            uv.u[1] = r1[0];
            uv.u[2] = r0[1];
            uv.u[3] = r1[1];
            int j = (2 * s + hi) ^ (r31 & 7);
            f16x8 v0 = *(const f16x8*)&Vb[r31 * 64 + j * 8];
            f16x8 v1 = *(const f16x8*)&Vb[(32 + r31) * 64 + j * 8];
            o0 = __builtin_amdgcn_mfma_f32_32x32x16_f16(v0, uv.v, o0, 0, 0, 0);
            o1 = __builtin_amdgcn_mfma_f32_32x32x16_f16(v1, uv.v, o1, 0, 0, 0);
        }
        __builtin_amdgcn_s_setprio(0);

        // l update off the critical path; cross-half sum via permlane
        {
            float2 rp = xhalf_pair(rs);
            l += rp.x + rp.y;
        }
    }
#undef STAGE_PAIR

    // ---- merge group B partials into group A, then store (LDS reused, staging done) ----
    __syncthreads();
    float* Ko = (float*)Klds;  // 4 waves x 64 lanes x 32 f32 = 32 KB exactly
    float* Vm = (float*)Vlds;  // m,l pairs
    if (w >= 4) {
        const int slot = ((w - 4) * 64 + lane) * 32;
#pragma unroll
        for (int c = 0; c < 4; ++c) {
            f32x4 t;
#pragma unroll
            for (int i = 0; i < 4; ++i) t[i] = o0[c * 4 + i];
            *(f32x4*)&Ko[slot + c * 4] = t;
#pragma unroll
            for (int i = 0; i < 4; ++i) t[i] = o1[c * 4 + i];
            *(f32x4*)&Ko[slot + 16 + c * 4] = t;
        }
        Vm[((w - 4) * 64 + lane) * 2] = m;
        Vm[((w - 4) * 64 + lane) * 2 + 1] = l;
    }
    __syncthreads();
    if (w < 4) {
        const int slot = (w * 64 + lane) * 32;
        float mB = Vm[(w * 64 + lane) * 2];
        float lB = Vm[(w * 64 + lane) * 2 + 1];
        float mS = fmaxf(m, mB);
        float sA = exp2f(m - mS), sB = exp2f(mB - mS);
        float linv = 1.0f / (l * sA + lB * sB);
        sA *= linv;
        sB *= linv;
        f16* yb = y + qrow * 1024 + h * 64 + hi * 4;
#pragma unroll
        for (int rg = 0; rg < 4; ++rg) {
            f32x4 pB0 = *(const f32x4*)&Ko[slot + rg * 4];
            f32x4 pB1 = *(const f32x4*)&Ko[slot + 16 + rg * 4];
            f16x4 ov;
#pragma unroll
            for (int i = 0; i < 4; ++i) ov[i] = (f16)(o0[rg * 4 + i] * sA + pB0[i] * sB);
            *(f16x4*)&yb[rg * 8] = ov;
#pragma unroll
            for (int i = 0; i < 4; ++i) ov[i] = (f16)(o1[rg * 4 + i] * sA + pB1[i] * sB);
            *(f16x4*)&yb[32 + rg * 8] = ov;
        }
    }
}

extern "C" void kernel_launch(void* const* d_in, const int* in_sizes, int n_in, void* d_out,
                              int out_size, void* d_ws, size_t ws_size, hipStream_t stream) {
    const float* q = (const float*)d_in[0];
    const float* k = (const float*)d_in[1];
    const float* v = (const float*)d_in[2];
    const float* fr = (const float*)d_in[3];
    const float* wq = (const float*)d_in[4];
    const float* wk = (const float*)d_in[5];
    const float* wv = (const float*)d_in[6];
    const float* wo = (const float*)d_in[7];
    char* ws = (char*)d_ws;

    float* cosT = (float*)(ws + 0);
    float* sinT = (float*)(ws + 262144);
    f16* qh = (f16*)(ws + 524288);
    f16* kh = (f16*)(ws + 8912896);
    f16* vh = (f16*)(ws + 17301504);
    f16* wqh = (f16*)(ws + 25690112);
    f16* wkh = (f16*)(ws + 27787264);
    f16* wvh = (f16*)(ws + 29884416);
    f16* woh = (f16*)(ws + 31981568);
    f16* Qp = (f16*)(ws + 34078720);
    f16* Kp = (f16*)(ws + 42467328);
    f16* Vp = (f16*)(ws + 50855936);
    // qh/kh are dead after the QKV GEMM: alias Vt and y over them
    f16* Vt = (f16*)(ws + 524288);
    f16* yh = (f16*)(ws + 8912896);

    k_trig<<<256, 256, 0, stream>>>(fr, cosT, sinT);
    k_cvt<<<16384, 256, 0, stream>>>(q, k, v, wq, wk, wv, wo, qh, kh, vh, wqh, wkh, wvh, woh);
    dim3 gq(32, 8, 3);
    k_gemm_qkv<<<gq, 256, 0, stream>>>(qh, kh, vh, wqh, wkh, wvh, Qp, Kp, Vp);
    k_rope<<<4096, 256, 0, stream>>>(Qp, Kp, cosT, sinT);
    dim3 gt(32, 32);
    k_vtrans<<<gt, 256, 0, stream>>>(Vp, Vt);
    dim3 gf(32, 16);
    k_flash<<<gf, 512, 0, stream>>>(Qp, Kp, Vt, yh);
    dim3 go(32, 8);
    k_gemm_out<<<go, 256, 0, stream>>>(yh, woh, (float*)d_out);
}

// Round 10
// 161.004 us; speedup vs baseline: 1.3720x; 1.0266x over previous
//
#include <hip/hip_runtime.h>
#include <stdint.h>

#define Bd 2
#define Td 2048
#define Cd 1024
#define Hd 16
#define HDd 64
#define BT 4096

typedef _Float16 f16;
typedef __attribute__((ext_vector_type(8))) _Float16 f16x8;
typedef __attribute__((ext_vector_type(4))) _Float16 f16x4;
typedef __attribute__((ext_vector_type(2))) _Float16 f16x2;
typedef __attribute__((ext_vector_type(4))) float f32x4;
typedef __attribute__((ext_vector_type(16))) float f32x16;
typedef __attribute__((ext_vector_type(2))) unsigned uint2v;

#define GLD_LDS16(gptr, lptr)                                                        \
    __builtin_amdgcn_global_load_lds((const __attribute__((address_space(1))) void*)(gptr), \
                                     (__attribute__((address_space(3))) void*)(lptr), 16, 0, 0)

#define MAX3(a, b, c) fmaxf(fmaxf(a, b), c)

// cross-half (lane i <-> lane i^32) value pair via permlane32_swap intrinsic (SSA-safe).
__device__ __forceinline__ float2 xhalf_pair(float v) {
    uint2v r = __builtin_amdgcn_permlane32_swap(__float_as_uint(v), __float_as_uint(v), false, false);
    unsigned lo = r[0], hi = r[1];
    float2 out;
    out.x = __uint_as_float(lo);
    out.y = __uint_as_float(hi);
    return out;
}

// ---------------- trig table: interleaved {cos,sin} of freqs (T x 32) ----------------
__global__ void k_trig(const float* __restrict__ freqs, float2* __restrict__ csT) {
    int i = blockIdx.x * 256 + threadIdx.x;  // 65536 total
    float f = freqs[i];
    float2 cs;
    cs.x = cosf(f);
    cs.y = sinf(f);
    csT[i] = cs;
}

// ---------------- f32 -> f16 conversion (q,k,v,Wq,Wk,Wv,Wo) ----------------
__global__ void k_cvt(const float* __restrict__ q, const float* __restrict__ k,
                      const float* __restrict__ v, const float* __restrict__ wq,
                      const float* __restrict__ wk, const float* __restrict__ wv,
                      const float* __restrict__ wo, f16* __restrict__ qh, f16* __restrict__ kh,
                      f16* __restrict__ vh, f16* __restrict__ wqh, f16* __restrict__ wkh,
                      f16* __restrict__ wvh, f16* __restrict__ woh) {
    int g = blockIdx.x * 256 + threadIdx.x;  // float4 groups, 4194304 total
    const float* src;
    f16* dst;
    int base;
    if (g < 1048576)      { src = q;  dst = qh;  base = 0; }
    else if (g < 2097152) { src = k;  dst = kh;  base = 1048576; }
    else if (g < 3145728) { src = v;  dst = vh;  base = 2097152; }
    else if (g < 3407872) { src = wq; dst = wqh; base = 3145728; }
    else if (g < 3670016) { src = wk; dst = wkh; base = 3407872; }
    else if (g < 3932160) { src = wv; dst = wvh; base = 3670016; }
    else                  { src = wo; dst = woh; base = 3932160; }
    int i = g - base;
    float4 val = reinterpret_cast<const float4*>(src)[i];
    f16x4 o;
    o[0] = (f16)val.x; o[1] = (f16)val.y; o[2] = (f16)val.z; o[3] = (f16)val.w;
    reinterpret_cast<f16x4*>(dst)[i] = o;
}

// ---------------- shared GEMM main loop (BK=64, both-sides XOR swizzle) ----------------
// computes acc[4][4] (f32x4 each) for out[m0+wm+i*16+g*4+r][n0+wn+j*16+r15]
#define GEMM_MAINLOOP(A, W)                                                                  \
    const int tid = threadIdx.x;                                                             \
    const int lane = tid & 63, w = tid >> 6;                                                 \
    const int g = lane >> 4, r15 = lane & 15;                                                \
    const int m0 = blockIdx.x * 128, n0 = blockIdx.y * 128;                                  \
    const int wm = (w >> 1) * 64, wn = (w & 1) * 64;                                         \
    const f32x4 zero4 = {0.f, 0.f, 0.f, 0.f};                                                \
    f32x4 acc[4][4];                                                                         \
    _Pragma("unroll") for (int i = 0; i < 4; ++i) {                                          \
        _Pragma("unroll") for (int j = 0; j < 4; ++j) acc[i][j] = zero4;                     \
    }                                                                                        \
    const int srow0 = tid >> 3;                                                              \
    const int sj = tid & 7;                                                                  \
    for (int k0 = 0; k0 < Cd; k0 += 64) {                                                    \
        _Pragma("unroll") for (int c = 0; c < 4; ++c) {                                      \
            int row = c * 32 + srow0;                                                        \
            int ch = sj ^ (row & 7);                                                         \
            GLD_LDS16(A + (m0 + row) * Cd + k0 + ch * 8, (f16*)Alds + (c * 256 + w * 64) * 8); \
            GLD_LDS16(W + (n0 + row) * Cd + k0 + ch * 8, (f16*)Blds + (c * 256 + w * 64) * 8); \
        }                                                                                    \
        __syncthreads();                                                                     \
        _Pragma("unroll") for (int half = 0; half < 2; ++half) {                             \
            f16x8 af[4], bf[4];                                                              \
            _Pragma("unroll") for (int t = 0; t < 4; ++t) {                                  \
                int cidx = ((half << 2) | g) ^ (r15 & 7);                                    \
                af[t] = *(const f16x8*)&Alds[(wm + t * 16 + r15) * 64 + cidx * 8];           \
                bf[t] = *(const f16x8*)&Blds[(wn + t * 16 + r15) * 64 + cidx * 8];           \
            }                                                                                \
            _Pragma("unroll") for (int i = 0; i < 4; ++i) {                                  \
                _Pragma("unroll") for (int j = 0; j < 4; ++j) acc[i][j] =                    \
                    __builtin_amdgcn_mfma_f32_16x16x32_f16(af[i], bf[j], acc[i][j], 0, 0, 0); \
            }                                                                                \
        }                                                                                    \
        __syncthreads();                                                                     \
    }

// ---------------- Q/K projection GEMM with fused RoPE epilogue ----------------
// z = blockIdx.z: 0 -> Q, 1 -> K. RoPE on the f32 accumulator: pair partner is the
// adjacent lane (d and d^1 differ in r15 bit0 -> __shfl_xor(.,1) = DPP quad-perm).
__global__ __launch_bounds__(256) void k_gemm_qk(const f16* __restrict__ qh,
                                                 const f16* __restrict__ kh,
                                                 const f16* __restrict__ wqh,
                                                 const f16* __restrict__ wkh,
                                                 f16* __restrict__ Qp, f16* __restrict__ Kp,
                                                 const float2* __restrict__ csT) {
    __shared__ __attribute__((aligned(16))) f16 Alds[128 * 64];
    __shared__ __attribute__((aligned(16))) f16 Blds[128 * 64];
    const int z = blockIdx.z;
    const f16* A = z ? kh : qh;
    const f16* W = z ? wkh : wqh;
    f16* outp = z ? Kp : Qp;
    GEMM_MAINLOOP(A, W)
#pragma unroll
    for (int i = 0; i < 4; ++i) {
#pragma unroll
        for (int j = 0; j < 4; ++j) {
#pragma unroll
            for (int r = 0; r < 4; ++r) {
                int row = m0 + wm + i * 16 + g * 4 + r;
                int col = n0 + wn + j * 16 + r15;
                float own = acc[i][j][r];
                float par = __shfl_xor(own, 1, 64);
                float2 cs = csT[(row & 2047) * 32 + ((j * 16 + r15) >> 1)];
                float val = (r15 & 1) ? fmaf(par, cs.y, own * cs.x)    // odd d: x0*s + x1*c
                                      : fmaf(own, cs.x, -par * cs.y);  // even d: x0*c - x1*s
                outp[row * Cd + col] = (f16)val;
            }
        }
    }
}

// ---------------- V projection GEMM with fused transpose epilogue -> Vt[bh][d][t] ----------------
__global__ __launch_bounds__(256) void k_gemm_v(const f16* __restrict__ vh,
                                                const f16* __restrict__ wvh,
                                                f16* __restrict__ Vt) {
    __shared__ __attribute__((aligned(16))) f16 Alds[128 * 64];
    __shared__ __attribute__((aligned(16))) f16 Blds[128 * 64];
    __shared__ __attribute__((aligned(16))) f16 Clds[128 * 136];  // [col][row], 136 pad -> 16B-aligned rows
    GEMM_MAINLOOP(vh, wvh)
    // store acc transposed into Clds[col][row]
#pragma unroll
    for (int i = 0; i < 4; ++i) {
#pragma unroll
        for (int j = 0; j < 4; ++j) {
#pragma unroll
            for (int r = 0; r < 4; ++r) {
                Clds[(wn + j * 16 + r15) * 136 + wm + i * 16 + g * 4 + r] = (f16)acc[i][j][r];
            }
        }
    }
    __syncthreads();
    // each thread: one (h,d) output row half (64 t), vectorized b128 LDS reads + 16B stores
    const int orow = tid >> 1;        // 0..127: local col = (h,d) within this n-panel
    const int th = (tid & 1) * 64;    // t half
    const int gcol = n0 + orow;
    const int hh = gcol >> 6, dd = gcol & 63;
    const int bb = m0 >> 11;
    f16* dst = Vt + ((bb * 16 + hh) * 64 + dd) * 2048 + (m0 & 2047) + th;
#pragma unroll
    for (int c = 0; c < 8; ++c) {
        f16x8 vv = *(const f16x8*)&Clds[orow * 136 + th + c * 8];
        *(f16x8*)&dst[c * 8] = vv;
    }
}

// ---------------- output GEMM (f32 out) ----------------
__global__ __launch_bounds__(256) void k_gemm_out(const f16* __restrict__ yh,
                                                  const f16* __restrict__ woh,
                                                  float* __restrict__ out) {
    __shared__ __attribute__((aligned(16))) f16 Alds[128 * 64];
    __shared__ __attribute__((aligned(16))) f16 Blds[128 * 64];
    GEMM_MAINLOOP(yh, woh)
#pragma unroll
    for (int i = 0; i < 4; ++i) {
#pragma unroll
        for (int j = 0; j < 4; ++j) {
#pragma unroll
            for (int r = 0; r < 4; ++r) {
                int row = m0 + wm + i * 16 + g * 4 + r;
                int col = n0 + wn + j * 16 + r15;
                out[row * Cd + col] = acc[i][j][r];
            }
        }
    }
}

// ---------------- Flash attention (byte-identical to R9; control) ----------------
__global__ __launch_bounds__(512, 4) void k_flash(const f16* __restrict__ Qp,
                                                  const f16* __restrict__ Kp,
                                                  const f16* __restrict__ Vt,
                                                  f16* __restrict__ y) {
    __shared__ __attribute__((aligned(16))) f16 Klds[2 * 2 * 4096];  // [pairbuf][tilepar][64kv][64d]
    __shared__ __attribute__((aligned(16))) f16 Vlds[2 * 2 * 4096];  // [pairbuf][tilepar][64d][64kv]
    const int bh = blockIdx.x, b = bh >> 4, h = bh & 15;
    const int tid = threadIdx.x, lane = tid & 63, w = tid >> 6;
    const int r31 = lane & 31, hi = lane >> 5;
    const int g2 = w >> 2, qw = w & 3;

    const int srow = tid >> 3, sj = tid & 7;
    const f16* gK = Kp + (b * 2048 + srow) * 1024 + h * 64 + ((sj ^ (srow & 7)) * 8);
    const f16* gV = Vt + (bh * 64 + srow) * 2048 + ((sj ^ (srow & 7)) * 8);
    f16* lK = (f16*)Klds + w * 512;
    f16* lV = (f16*)Vlds + w * 512;

#define STAGE_PAIR(pb, pi)                                          \
    do {                                                            \
        GLD_LDS16(gK + (2 * (pi)) * 65536, lK + (pb) * 8192);       \
        GLD_LDS16(gK + (2 * (pi) + 1) * 65536, lK + (pb) * 8192 + 4096); \
        GLD_LDS16(gV + (2 * (pi)) * 64, lV + (pb) * 8192);          \
        GLD_LDS16(gV + (2 * (pi) + 1) * 64, lV + (pb) * 8192 + 4096);   \
    } while (0)

    const int qrow = b * 2048 + blockIdx.y * 128 + qw * 32 + r31;
    f16x8 qf[4];
    {
        const f16* qb = Qp + qrow * 1024 + h * 64 + hi * 8;
        const f16 sc = (f16)(0.125f * 1.44269504088896f);
#pragma unroll
        for (int dc = 0; dc < 4; ++dc) {
            f16x8 v = *(const f16x8*)(qb + dc * 16);
#pragma unroll
            for (int j = 0; j < 8; ++j) v[j] = v[j] * sc;
            qf[dc] = v;
        }
    }

    f32x16 o0, o1;
#pragma unroll
    for (int r = 0; r < 16; ++r) { o0[r] = 0.f; o1[r] = 0.f; }
    float m = -1e30f, l = 0.f;

    STAGE_PAIR(0, 0);

    for (int it = 0; it < 16; ++it) {
        __builtin_amdgcn_s_barrier();
        if (it < 15) {
            STAGE_PAIR((it + 1) & 1, it + 1);
            asm volatile("s_waitcnt vmcnt(4)" ::: "memory");
        } else {
            asm volatile("s_waitcnt vmcnt(0)" ::: "memory");
        }
        __builtin_amdgcn_sched_barrier(0);
        __builtin_amdgcn_s_barrier();
        const f16* Kb = (const f16*)Klds + (it & 1) * 8192 + g2 * 4096;
        const f16* Vb = (const f16*)Vlds + (it & 1) * 8192 + g2 * 4096;

        f32x16 s0, s1;
#pragma unroll
        for (int r = 0; r < 16; ++r) { s0[r] = 0.f; s1[r] = 0.f; }
        __builtin_amdgcn_s_setprio(1);
#pragma unroll
        for (int dc = 0; dc < 4; ++dc) {
            int j = (2 * dc + hi) ^ (r31 & 7);
            f16x8 k0 = *(const f16x8*)&Kb[r31 * 64 + j * 8];
            f16x8 k1 = *(const f16x8*)&Kb[(32 + r31) * 64 + j * 8];
            s0 = __builtin_amdgcn_mfma_f32_32x32x16_f16(k0, qf[dc], s0, 0, 0, 0);
            s1 = __builtin_amdgcn_mfma_f32_32x32x16_f16(k1, qf[dc], s1, 0, 0, 0);
        }
        __builtin_amdgcn_s_setprio(0);

        float t16[16];
#pragma unroll
        for (int r = 0; r < 16; ++r) t16[r] = fmaxf(s0[r], s1[r]);
        float p0 = MAX3(t16[0], t16[1], t16[2]);
        float p1 = MAX3(t16[3], t16[4], t16[5]);
        float p2 = MAX3(t16[6], t16[7], t16[8]);
        float p3 = MAX3(t16[9], t16[10], t16[11]);
        float p4 = MAX3(t16[12], t16[13], t16[14]);
        float pmax = fmaxf(MAX3(p0, p1, p2), MAX3(p3, p4, t16[15]));
        {
            float2 pm = xhalf_pair(pmax);
            pmax = fmaxf(pm.x, pm.y);
        }
        if (__any(pmax > m + 8.0f)) {
            float mn = fmaxf(m, pmax);
            float cr = exp2f(m - mn);
            m = mn;
            l *= cr;
#pragma unroll
            for (int r = 0; r < 16; ++r) { o0[r] *= cr; o1[r] *= cr; }
        }
#pragma unroll
        for (int r = 0; r < 16; ++r) s0[r] = exp2f(s0[r] - m);
#pragma unroll
        for (int r = 0; r < 16; ++r) s1[r] = exp2f(s1[r] - m);
        float a16[16];
#pragma unroll
        for (int r = 0; r < 16; ++r) a16[r] = s0[r] + s1[r];
#pragma unroll
        for (int r = 0; r < 8; ++r) a16[r] += a16[r + 8];
#pragma unroll
        for (int r = 0; r < 4; ++r) a16[r] += a16[r + 4];
        float rs = (a16[0] + a16[1]) + (a16[2] + a16[3]);

        unsigned pk[16];
#pragma unroll
        for (int i = 0; i < 8; ++i) {
            auto ha = __builtin_amdgcn_cvt_pkrtz(s0[2 * i], s0[2 * i + 1]);
            __builtin_memcpy(&pk[i], &ha, 4);
            auto hb = __builtin_amdgcn_cvt_pkrtz(s1[2 * i], s1[2 * i + 1]);
            __builtin_memcpy(&pk[8 + i], &hb, 4);
        }

        __builtin_amdgcn_s_setprio(1);
#pragma unroll
        for (int s = 0; s < 4; ++s) {
            const int base = (s >> 1) * 8 + (s & 1) * 4;
            uint2v r0 = __builtin_amdgcn_permlane32_swap(pk[base + 0], pk[base + 2], false, false);
            uint2v r1 = __builtin_amdgcn_permlane32_swap(pk[base + 1], pk[base + 3], false, false);
            union { unsigned u[4]; f16x8 v; } uv;
            uv.u[0] = r0[0];
            uv.u[1] = r1[0];
            uv.u[2] = r0[1];
            uv.u[3] = r1[1];
            int j = (2 * s + hi) ^ (r31 & 7);
            f16x8 v0 = *(const f16x8*)&Vb[r31 * 64 + j * 8];
            f16x8 v1 = *(const f16x8*)&Vb[(32 + r31) * 64 + j * 8];
            o0 = __builtin_amdgcn_mfma_f32_32x32x16_f16(v0, uv.v, o0, 0, 0, 0);
            o1 = __builtin_amdgcn_mfma_f32_32x32x16_f16(v1, uv.v, o1, 0, 0, 0);
        }
        __builtin_amdgcn_s_setprio(0);

        {
            float2 rp = xhalf_pair(rs);
            l += rp.x + rp.y;
        }
    }
#undef STAGE_PAIR

    __syncthreads();
    float* Ko = (float*)Klds;
    float* Vm = (float*)Vlds;
    if (w >= 4) {
        const int slot = ((w - 4) * 64 + lane) * 32;
#pragma unroll
        for (int c = 0; c < 4; ++c) {
            f32x4 t;
#pragma unroll
            for (int i = 0; i < 4; ++i) t[i] = o0[c * 4 + i];
            *(f32x4*)&Ko[slot + c * 4] = t;
#pragma unroll
            for (int i = 0; i < 4; ++i) t[i] = o1[c * 4 + i];
            *(f32x4*)&Ko[slot + 16 + c * 4] = t;
        }
        Vm[((w - 4) * 64 + lane) * 2] = m;
        Vm[((w - 4) * 64 + lane) * 2 + 1] = l;
    }
    __syncthreads();
    if (w < 4) {
        const int slot = (w * 64 + lane) * 32;
        float mB = Vm[(w * 64 + lane) * 2];
        float lB = Vm[(w * 64 + lane) * 2 + 1];
        float mS = fmaxf(m, mB);
        float sA = exp2f(m - mS), sB = exp2f(mB - mS);
        float linv = 1.0f / (l * sA + lB * sB);
        sA *= linv;
        sB *= linv;
        f16* yb = y + qrow * 1024 + h * 64 + hi * 4;
#pragma unroll
        for (int rg = 0; rg < 4; ++rg) {
            f32x4 pB0 = *(const f32x4*)&Ko[slot + rg * 4];
            f32x4 pB1 = *(const f32x4*)&Ko[slot + 16 + rg * 4];
            f16x4 ov;
#pragma unroll
            for (int i = 0; i < 4; ++i) ov[i] = (f16)(o0[rg * 4 + i] * sA + pB0[i] * sB);
            *(f16x4*)&yb[rg * 8] = ov;
#pragma unroll
            for (int i = 0; i < 4; ++i) ov[i] = (f16)(o1[rg * 4 + i] * sA + pB1[i] * sB);
            *(f16x4*)&yb[32 + rg * 8] = ov;
        }
    }
}

extern "C" void kernel_launch(void* const* d_in, const int* in_sizes, int n_in, void* d_out,
                              int out_size, void* d_ws, size_t ws_size, hipStream_t stream) {
    const float* q = (const float*)d_in[0];
    const float* k = (const float*)d_in[1];
    const float* v = (const float*)d_in[2];
    const float* fr = (const float*)d_in[3];
    const float* wq = (const float*)d_in[4];
    const float* wk = (const float*)d_in[5];
    const float* wv = (const float*)d_in[6];
    const float* wo = (const float*)d_in[7];
    char* ws = (char*)d_ws;

    float2* csT = (float2*)(ws + 0);       // 65536 * 8B = 524288
    f16* qh = (f16*)(ws + 524288);
    f16* kh = (f16*)(ws + 8912896);
    f16* vh = (f16*)(ws + 17301504);
    f16* wqh = (f16*)(ws + 25690112);
    f16* wkh = (f16*)(ws + 27787264);
    f16* wvh = (f16*)(ws + 29884416);
    f16* woh = (f16*)(ws + 31981568);
    f16* Qp = (f16*)(ws + 34078720);
    f16* Kp = (f16*)(ws + 42467328);
    f16* Vt = (f16*)(ws + 50855936);       // written by k_gemm_v (transposed), read by flash
    f16* yh = (f16*)(ws + 8912896);        // aliases kh (dead after k_gemm_qk z=1)

    k_trig<<<256, 256, 0, stream>>>(fr, csT);
    k_cvt<<<16384, 256, 0, stream>>>(q, k, v, wq, wk, wv, wo, qh, kh, vh, wqh, wkh, wvh, woh);
    dim3 gqk(32, 8, 2);
    k_gemm_qk<<<gqk, 256, 0, stream>>>(qh, kh, wqh, wkh, Qp, Kp, csT);
    dim3 gv(32, 8);
    k_gemm_v<<<gv, 256, 0, stream>>>(vh, wvh, Vt);
    dim3 gf(32, 16);
    k_flash<<<gf, 512, 0, stream>>>(Qp, Kp, Vt, yh);
    dim3 go(32, 8);
    k_gemm_out<<<go, 256, 0, stream>>>(yh, woh, (float*)d_out);
}

// Round 11
// 135.083 us; speedup vs baseline: 1.6352x; 1.1919x over previous
//
#include <hip/hip_runtime.h>
#include <stdint.h>

#define Bd 2
#define Td 2048
#define Cd 1024
#define Hd 16
#define HDd 64
#define BT 4096

typedef _Float16 f16;
typedef __attribute__((ext_vector_type(8))) _Float16 f16x8;
typedef __attribute__((ext_vector_type(4))) _Float16 f16x4;
typedef __attribute__((ext_vector_type(2))) _Float16 f16x2;
typedef __attribute__((ext_vector_type(4))) float f32x4;
typedef __attribute__((ext_vector_type(16))) float f32x16;
typedef __attribute__((ext_vector_type(2))) unsigned uint2v;

#define GLD_LDS16(gptr, lptr)                                                        \
    __builtin_amdgcn_global_load_lds((const __attribute__((address_space(1))) void*)(gptr), \
                                     (__attribute__((address_space(3))) void*)(lptr), 16, 0, 0)

#define MAX3(a, b, c) fmaxf(fmaxf(a, b), c)

// cross-half (lane i <-> lane i^32) value pair via permlane32_swap intrinsic (SSA-safe).
__device__ __forceinline__ float2 xhalf_pair(float v) {
    uint2v r = __builtin_amdgcn_permlane32_swap(__float_as_uint(v), __float_as_uint(v), false, false);
    unsigned lo = r[0], hi = r[1];
    float2 out;
    out.x = __uint_as_float(lo);
    out.y = __uint_as_float(hi);
    return out;
}

// ---------------- f32 -> f16 conversion (q,k,v,Wq,Wk,Wv,Wo) + fused trig table ----------------
// blocks [0, 16384): float4->f16x4 conversion; blocks [16384, 16640): {cos,sin} table.
__global__ void k_cvt(const float* __restrict__ q, const float* __restrict__ k,
                      const float* __restrict__ v, const float* __restrict__ wq,
                      const float* __restrict__ wk, const float* __restrict__ wv,
                      const float* __restrict__ wo, f16* __restrict__ qh, f16* __restrict__ kh,
                      f16* __restrict__ vh, f16* __restrict__ wqh, f16* __restrict__ wkh,
                      f16* __restrict__ wvh, f16* __restrict__ woh,
                      const float* __restrict__ freqs, float2* __restrict__ csT) {
    int g = blockIdx.x * 256 + threadIdx.x;
    if (g >= 4194304) {  // trig tail: 65536 elems
        int i = g - 4194304;
        float f = freqs[i];
        float2 cs;
        cs.x = cosf(f);
        cs.y = sinf(f);
        csT[i] = cs;
        return;
    }
    const float* src;
    f16* dst;
    int base;
    if (g < 1048576)      { src = q;  dst = qh;  base = 0; }
    else if (g < 2097152) { src = k;  dst = kh;  base = 1048576; }
    else if (g < 3145728) { src = v;  dst = vh;  base = 2097152; }
    else if (g < 3407872) { src = wq; dst = wqh; base = 3145728; }
    else if (g < 3670016) { src = wk; dst = wkh; base = 3407872; }
    else if (g < 3932160) { src = wv; dst = wvh; base = 3670016; }
    else                  { src = wo; dst = woh; base = 3932160; }
    int i = g - base;
    float4 val = reinterpret_cast<const float4*>(src)[i];
    f16x4 o;
    o[0] = (f16)val.x; o[1] = (f16)val.y; o[2] = (f16)val.z; o[3] = (f16)val.w;
    reinterpret_cast<f16x4*>(dst)[i] = o;
}

// ---------------- shared GEMM main loop (BK=64, both-sides XOR swizzle, 128x128 tile) ----------
#define GEMM_MAINLOOP(A, W)                                                                  \
    const int tid = threadIdx.x;                                                             \
    const int lane = tid & 63, w = tid >> 6;                                                 \
    const int g = lane >> 4, r15 = lane & 15;                                                \
    const int m0 = blockIdx.x * 128, n0 = blockIdx.y * 128;                                  \
    const int wm = (w >> 1) * 64, wn = (w & 1) * 64;                                         \
    const f32x4 zero4 = {0.f, 0.f, 0.f, 0.f};                                                \
    f32x4 acc[4][4];                                                                         \
    _Pragma("unroll") for (int i = 0; i < 4; ++i) {                                          \
        _Pragma("unroll") for (int j = 0; j < 4; ++j) acc[i][j] = zero4;                     \
    }                                                                                        \
    const int srow0 = tid >> 3;                                                              \
    const int sj = tid & 7;                                                                  \
    for (int k0 = 0; k0 < Cd; k0 += 64) {                                                    \
        _Pragma("unroll") for (int c = 0; c < 4; ++c) {                                      \
            int row = c * 32 + srow0;                                                        \
            int ch = sj ^ (row & 7);                                                         \
            GLD_LDS16(A + (m0 + row) * Cd + k0 + ch * 8, Alds + (c * 256 + w * 64) * 8);     \
            GLD_LDS16(W + (n0 + row) * Cd + k0 + ch * 8, Blds + (c * 256 + w * 64) * 8);     \
        }                                                                                    \
        __syncthreads();                                                                     \
        _Pragma("unroll") for (int half = 0; half < 2; ++half) {                             \
            f16x8 af[4], bf[4];                                                              \
            _Pragma("unroll") for (int t = 0; t < 4; ++t) {                                  \
                int cidx = ((half << 2) | g) ^ (r15 & 7);                                    \
                af[t] = *(const f16x8*)&Alds[(wm + t * 16 + r15) * 64 + cidx * 8];           \
                bf[t] = *(const f16x8*)&Blds[(wn + t * 16 + r15) * 64 + cidx * 8];           \
            }                                                                                \
            _Pragma("unroll") for (int i = 0; i < 4; ++i) {                                  \
                _Pragma("unroll") for (int j = 0; j < 4; ++j) acc[i][j] =                    \
                    __builtin_amdgcn_mfma_f32_16x16x32_f16(af[i], bf[j], acc[i][j], 0, 0, 0); \
            }                                                                                \
        }                                                                                    \
        __syncthreads();                                                                     \
    }

// ---------------- fused QKV projection GEMM: z=0 Q(+rope), z=1 K(+rope), z=2 V(+transpose) ----
// grid (32, 8, 3) = 768 blocks = 3/CU = 3 waves/SIMD (vs 1 before: the GEMMs were
// latency-exposed at 1 block/CU). LDS: A/B panels 32KB; z=2 epilogue reuses the same
// buffer (all reads drained by the main loop's trailing barrier) as Clds[128][136].
__global__ __launch_bounds__(256, 3) void k_gemm_qkv(
    const f16* __restrict__ qh, const f16* __restrict__ kh, const f16* __restrict__ vh,
    const f16* __restrict__ wqh, const f16* __restrict__ wkh, const f16* __restrict__ wvh,
    f16* __restrict__ Qp, f16* __restrict__ Kp, f16* __restrict__ Vt,
    const float2* __restrict__ csT) {
    __shared__ __attribute__((aligned(16))) char smem[34816];
    f16* Alds = (f16*)smem;
    f16* Blds = (f16*)(smem + 16384);
    const int z = blockIdx.z;
    const f16* A = (z == 0) ? qh : (z == 1) ? kh : vh;
    const f16* W = (z == 0) ? wqh : (z == 1) ? wkh : wvh;
    GEMM_MAINLOOP(A, W)
    if (z < 2) {
        // RoPE on the f32 accumulator; pair partner = adjacent lane (DPP shuffle)
        f16* outp = z ? Kp : Qp;
#pragma unroll
        for (int i = 0; i < 4; ++i) {
#pragma unroll
            for (int j = 0; j < 4; ++j) {
#pragma unroll
                for (int r = 0; r < 4; ++r) {
                    int row = m0 + wm + i * 16 + g * 4 + r;
                    int col = n0 + wn + j * 16 + r15;
                    float own = acc[i][j][r];
                    float par = __shfl_xor(own, 1, 64);
                    float2 cs = csT[(row & 2047) * 32 + ((j * 16 + r15) >> 1)];
                    float val = (r15 & 1) ? fmaf(par, cs.y, own * cs.x)
                                          : fmaf(own, cs.x, -par * cs.y);
                    outp[row * Cd + col] = (f16)val;
                }
            }
        }
    } else {
        // transpose epilogue -> Vt[bh][d][t]; reuse smem as Clds[col][row], stride 136
        f16* Clds = (f16*)smem;
#pragma unroll
        for (int i = 0; i < 4; ++i) {
#pragma unroll
            for (int j = 0; j < 4; ++j) {
                f16x4 pv;
#pragma unroll
                for (int r = 0; r < 4; ++r) pv[r] = (f16)acc[i][j][r];
                *(f16x4*)&Clds[(wn + j * 16 + r15) * 136 + wm + i * 16 + g * 4] = pv;
            }
        }
        __syncthreads();
        const int orow = tid >> 1;
        const int th = (tid & 1) * 64;
        const int gcol = n0 + orow;
        const int hh = gcol >> 6, dd = gcol & 63;
        const int bb = m0 >> 11;
        f16* dst = Vt + ((bb * 16 + hh) * 64 + dd) * 2048 + (m0 & 2047) + th;
#pragma unroll
        for (int c = 0; c < 8; ++c) {
            f16x8 vv = *(const f16x8*)&Clds[orow * 136 + th + c * 8];
            *(f16x8*)&dst[c * 8] = vv;
        }
    }
}

// ---------------- output GEMM (f32 out), 128x64 tile -> 512 blocks = 2/CU ----------------
__global__ __launch_bounds__(256, 4) void k_gemm_out(const f16* __restrict__ yh,
                                                     const f16* __restrict__ woh,
                                                     float* __restrict__ out) {
    __shared__ __attribute__((aligned(16))) f16 Alds[128 * 64];
    __shared__ __attribute__((aligned(16))) f16 Blds[64 * 64];
    const int tid = threadIdx.x;
    const int lane = tid & 63, w = tid >> 6;
    const int g = lane >> 4, r15 = lane & 15;
    const int m0 = blockIdx.x * 128, n0 = blockIdx.y * 64;
    const int wm = (w >> 1) * 64, wn = (w & 1) * 32;
    const f32x4 zero4 = {0.f, 0.f, 0.f, 0.f};
    f32x4 acc[4][2];
#pragma unroll
    for (int i = 0; i < 4; ++i) {
#pragma unroll
        for (int j = 0; j < 2; ++j) acc[i][j] = zero4;
    }
    const int srow0 = tid >> 3;
    const int sj = tid & 7;
    for (int k0 = 0; k0 < Cd; k0 += 64) {
#pragma unroll
        for (int c = 0; c < 4; ++c) {
            int row = c * 32 + srow0;
            int ch = sj ^ (row & 7);
            GLD_LDS16(yh + (m0 + row) * Cd + k0 + ch * 8, (f16*)Alds + (c * 256 + w * 64) * 8);
        }
#pragma unroll
        for (int c = 0; c < 2; ++c) {
            int row = c * 32 + srow0;
            int ch = sj ^ (row & 7);
            GLD_LDS16(woh + (n0 + row) * Cd + k0 + ch * 8, (f16*)Blds + (c * 256 + w * 64) * 8);
        }
        __syncthreads();
#pragma unroll
        for (int half = 0; half < 2; ++half) {
            f16x8 af[4], bf[2];
            int cidx = ((half << 2) | g) ^ (r15 & 7);
#pragma unroll
            for (int t = 0; t < 4; ++t)
                af[t] = *(const f16x8*)&Alds[(wm + t * 16 + r15) * 64 + cidx * 8];
#pragma unroll
            for (int t = 0; t < 2; ++t)
                bf[t] = *(const f16x8*)&Blds[(wn + t * 16 + r15) * 64 + cidx * 8];
#pragma unroll
            for (int i = 0; i < 4; ++i) {
#pragma unroll
                for (int j = 0; j < 2; ++j)
                    acc[i][j] =
                        __builtin_amdgcn_mfma_f32_16x16x32_f16(af[i], bf[j], acc[i][j], 0, 0, 0);
            }
        }
        __syncthreads();
    }
#pragma unroll
    for (int i = 0; i < 4; ++i) {
#pragma unroll
        for (int j = 0; j < 2; ++j) {
#pragma unroll
            for (int r = 0; r < 4; ++r) {
                int row = m0 + wm + i * 16 + g * 4 + r;
                int col = n0 + wn + j * 16 + r15;
                out[row * Cd + col] = acc[i][j][r];
            }
        }
    }
}

// ---------------- Flash attention (byte-identical to R9/R10; control) ----------------
__global__ __launch_bounds__(512, 4) void k_flash(const f16* __restrict__ Qp,
                                                  const f16* __restrict__ Kp,
                                                  const f16* __restrict__ Vt,
                                                  f16* __restrict__ y) {
    __shared__ __attribute__((aligned(16))) f16 Klds[2 * 2 * 4096];
    __shared__ __attribute__((aligned(16))) f16 Vlds[2 * 2 * 4096];
    const int bh = blockIdx.x, b = bh >> 4, h = bh & 15;
    const int tid = threadIdx.x, lane = tid & 63, w = tid >> 6;
    const int r31 = lane & 31, hi = lane >> 5;
    const int g2 = w >> 2, qw = w & 3;

    const int srow = tid >> 3, sj = tid & 7;
    const f16* gK = Kp + (b * 2048 + srow) * 1024 + h * 64 + ((sj ^ (srow & 7)) * 8);
    const f16* gV = Vt + (bh * 64 + srow) * 2048 + ((sj ^ (srow & 7)) * 8);
    f16* lK = (f16*)Klds + w * 512;
    f16* lV = (f16*)Vlds + w * 512;

#define STAGE_PAIR(pb, pi)                                          \
    do {                                                            \
        GLD_LDS16(gK + (2 * (pi)) * 65536, lK + (pb) * 8192);       \
        GLD_LDS16(gK + (2 * (pi) + 1) * 65536, lK + (pb) * 8192 + 4096); \
        GLD_LDS16(gV + (2 * (pi)) * 64, lV + (pb) * 8192);          \
        GLD_LDS16(gV + (2 * (pi) + 1) * 64, lV + (pb) * 8192 + 4096);   \
    } while (0)

    const int qrow = b * 2048 + blockIdx.y * 128 + qw * 32 + r31;
    f16x8 qf[4];
    {
        const f16* qb = Qp + qrow * 1024 + h * 64 + hi * 8;
        const f16 sc = (f16)(0.125f * 1.44269504088896f);
#pragma unroll
        for (int dc = 0; dc < 4; ++dc) {
            f16x8 v = *(const f16x8*)(qb + dc * 16);
#pragma unroll
            for (int j = 0; j < 8; ++j) v[j] = v[j] * sc;
            qf[dc] = v;
        }
    }

    f32x16 o0, o1;
#pragma unroll
    for (int r = 0; r < 16; ++r) { o0[r] = 0.f; o1[r] = 0.f; }
    float m = -1e30f, l = 0.f;

    STAGE_PAIR(0, 0);

    for (int it = 0; it < 16; ++it) {
        __builtin_amdgcn_s_barrier();
        if (it < 15) {
            STAGE_PAIR((it + 1) & 1, it + 1);
            asm volatile("s_waitcnt vmcnt(4)" ::: "memory");
        } else {
            asm volatile("s_waitcnt vmcnt(0)" ::: "memory");
        }
        __builtin_amdgcn_sched_barrier(0);
        __builtin_amdgcn_s_barrier();
        const f16* Kb = (const f16*)Klds + (it & 1) * 8192 + g2 * 4096;
        const f16* Vb = (const f16*)Vlds + (it & 1) * 8192 + g2 * 4096;

        f32x16 s0, s1;
#pragma unroll
        for (int r = 0; r < 16; ++r) { s0[r] = 0.f; s1[r] = 0.f; }
        __builtin_amdgcn_s_setprio(1);
#pragma unroll
        for (int dc = 0; dc < 4; ++dc) {
            int j = (2 * dc + hi) ^ (r31 & 7);
            f16x8 k0 = *(const f16x8*)&Kb[r31 * 64 + j * 8];
            f16x8 k1 = *(const f16x8*)&Kb[(32 + r31) * 64 + j * 8];
            s0 = __builtin_amdgcn_mfma_f32_32x32x16_f16(k0, qf[dc], s0, 0, 0, 0);
            s1 = __builtin_amdgcn_mfma_f32_32x32x16_f16(k1, qf[dc], s1, 0, 0, 0);
        }
        __builtin_amdgcn_s_setprio(0);

        float t16[16];
#pragma unroll
        for (int r = 0; r < 16; ++r) t16[r] = fmaxf(s0[r], s1[r]);
        float p0 = MAX3(t16[0], t16[1], t16[2]);
        float p1 = MAX3(t16[3], t16[4], t16[5]);
        float p2 = MAX3(t16[6], t16[7], t16[8]);
        float p3 = MAX3(t16[9], t16[10], t16[11]);
        float p4 = MAX3(t16[12], t16[13], t16[14]);
        float pmax = fmaxf(MAX3(p0, p1, p2), MAX3(p3, p4, t16[15]));
        {
            float2 pm = xhalf_pair(pmax);
            pmax = fmaxf(pm.x, pm.y);
        }
        if (__any(pmax > m + 8.0f)) {
            float mn = fmaxf(m, pmax);
            float cr = exp2f(m - mn);
            m = mn;
            l *= cr;
#pragma unroll
            for (int r = 0; r < 16; ++r) { o0[r] *= cr; o1[r] *= cr; }
        }
#pragma unroll
        for (int r = 0; r < 16; ++r) s0[r] = exp2f(s0[r] - m);
#pragma unroll
        for (int r = 0; r < 16; ++r) s1[r] = exp2f(s1[r] - m);
        float a16[16];
#pragma unroll
        for (int r = 0; r < 16; ++r) a16[r] = s0[r] + s1[r];
#pragma unroll
        for (int r = 0; r < 8; ++r) a16[r] += a16[r + 8];
#pragma unroll
        for (int r = 0; r < 4; ++r) a16[r] += a16[r + 4];
        float rs = (a16[0] + a16[1]) + (a16[2] + a16[3]);

        unsigned pk[16];
#pragma unroll
        for (int i = 0; i < 8; ++i) {
            auto ha = __builtin_amdgcn_cvt_pkrtz(s0[2 * i], s0[2 * i + 1]);
            __builtin_memcpy(&pk[i], &ha, 4);
            auto hb = __builtin_amdgcn_cvt_pkrtz(s1[2 * i], s1[2 * i + 1]);
            __builtin_memcpy(&pk[8 + i], &hb, 4);
        }

        __builtin_amdgcn_s_setprio(1);
#pragma unroll
        for (int s = 0; s < 4; ++s) {
            const int base = (s >> 1) * 8 + (s & 1) * 4;
            uint2v r0 = __builtin_amdgcn_permlane32_swap(pk[base + 0], pk[base + 2], false, false);
            uint2v r1 = __builtin_amdgcn_permlane32_swap(pk[base + 1], pk[base + 3], false, false);
            union { unsigned u[4]; f16x8 v; } uv;
            uv.u[0] = r0[0];
            uv.u[1] = r1[0];
            uv.u[2] = r0[1];
            uv.u[3] = r1[1];
            int j = (2 * s + hi) ^ (r31 & 7);
            f16x8 v0 = *(const f16x8*)&Vb[r31 * 64 + j * 8];
            f16x8 v1 = *(const f16x8*)&Vb[(32 + r31) * 64 + j * 8];
            o0 = __builtin_amdgcn_mfma_f32_32x32x16_f16(v0, uv.v, o0, 0, 0, 0);
            o1 = __builtin_amdgcn_mfma_f32_32x32x16_f16(v1, uv.v, o1, 0, 0, 0);
        }
        __builtin_amdgcn_s_setprio(0);

        {
            float2 rp = xhalf_pair(rs);
            l += rp.x + rp.y;
        }
    }
#undef STAGE_PAIR

    __syncthreads();
    float* Ko = (float*)Klds;
    float* Vm = (float*)Vlds;
    if (w >= 4) {
        const int slot = ((w - 4) * 64 + lane) * 32;
#pragma unroll
        for (int c = 0; c < 4; ++c) {
            f32x4 t;
#pragma unroll
            for (int i = 0; i < 4; ++i) t[i] = o0[c * 4 + i];
            *(f32x4*)&Ko[slot + c * 4] = t;
#pragma unroll
            for (int i = 0; i < 4; ++i) t[i] = o1[c * 4 + i];
            *(f32x4*)&Ko[slot + 16 + c * 4] = t;
        }
        Vm[((w - 4) * 64 + lane) * 2] = m;
        Vm[((w - 4) * 64 + lane) * 2 + 1] = l;
    }
    __syncthreads();
    if (w < 4) {
        const int slot = (w * 64 + lane) * 32;
        float mB = Vm[(w * 64 + lane) * 2];
        float lB = Vm[(w * 64 + lane) * 2 + 1];
        float mS = fmaxf(m, mB);
        float sA = exp2f(m - mS), sB = exp2f(mB - mS);
        float linv = 1.0f / (l * sA + lB * sB);
        sA *= linv;
        sB *= linv;
        f16* yb = y + qrow * 1024 + h * 64 + hi * 4;
#pragma unroll
        for (int rg = 0; rg < 4; ++rg) {
            f32x4 pB0 = *(const f32x4*)&Ko[slot + rg * 4];
            f32x4 pB1 = *(const f32x4*)&Ko[slot + 16 + rg * 4];
            f16x4 ov;
#pragma unroll
            for (int i = 0; i < 4; ++i) ov[i] = (f16)(o0[rg * 4 + i] * sA + pB0[i] * sB);
            *(f16x4*)&yb[rg * 8] = ov;
#pragma unroll
            for (int i = 0; i < 4; ++i) ov[i] = (f16)(o1[rg * 4 + i] * sA + pB1[i] * sB);
            *(f16x4*)&yb[32 + rg * 8] = ov;
        }
    }
}

extern "C" void kernel_launch(void* const* d_in, const int* in_sizes, int n_in, void* d_out,
                              int out_size, void* d_ws, size_t ws_size, hipStream_t stream) {
    const float* q = (const float*)d_in[0];
    const float* k = (const float*)d_in[1];
    const float* v = (const float*)d_in[2];
    const float* fr = (const float*)d_in[3];
    const float* wq = (const float*)d_in[4];
    const float* wk = (const float*)d_in[5];
    const float* wv = (const float*)d_in[6];
    const float* wo = (const float*)d_in[7];
    char* ws = (char*)d_ws;

    float2* csT = (float2*)(ws + 0);
    f16* qh = (f16*)(ws + 524288);
    f16* kh = (f16*)(ws + 8912896);
    f16* vh = (f16*)(ws + 17301504);
    f16* wqh = (f16*)(ws + 25690112);
    f16* wkh = (f16*)(ws + 27787264);
    f16* wvh = (f16*)(ws + 29884416);
    f16* woh = (f16*)(ws + 31981568);
    f16* Qp = (f16*)(ws + 34078720);
    f16* Kp = (f16*)(ws + 42467328);
    f16* Vt = (f16*)(ws + 50855936);
    f16* yh = (f16*)(ws + 8912896);  // aliases kh (dead after k_gemm_qkv)

    k_cvt<<<16640, 256, 0, stream>>>(q, k, v, wq, wk, wv, wo, qh, kh, vh, wqh, wkh, wvh, woh,
                                     fr, csT);
    dim3 gqkv(32, 8, 3);
    k_gemm_qkv<<<gqkv, 256, 0, stream>>>(qh, kh, vh, wqh, wkh, wvh, Qp, Kp, Vt, csT);
    dim3 gf(32, 16);
    k_flash<<<gf, 512, 0, stream>>>(Qp, Kp, Vt, yh);
    dim3 go(32, 16);
    k_gemm_out<<<go, 256, 0, stream>>>(yh, woh, (float*)d_out);
}

// Round 13
// 124.316 us; speedup vs baseline: 1.7769x; 1.0866x over previous
//
#include <hip/hip_runtime.h>
#include <stdint.h>

#define Bd 2
#define Td 2048
#define Cd 1024
#define Hd 16
#define HDd 64
#define BT 4096

typedef _Float16 f16;
typedef __attribute__((ext_vector_type(8))) _Float16 f16x8;
typedef __attribute__((ext_vector_type(4))) _Float16 f16x4;
typedef __attribute__((ext_vector_type(2))) _Float16 f16x2;
typedef __attribute__((ext_vector_type(4))) float f32x4;
typedef __attribute__((ext_vector_type(16))) float f32x16;
typedef __attribute__((ext_vector_type(2))) unsigned uint2v;

#define GLD_LDS16(gptr, lptr)                                                        \
    __builtin_amdgcn_global_load_lds((const __attribute__((address_space(1))) void*)(gptr), \
                                     (__attribute__((address_space(3))) void*)(lptr), 16, 0, 0)

#define MAX3(a, b, c) fmaxf(fmaxf(a, b), c)
// raw v_exp_f32: exp2f() without -ffast-math lowers to a ~6-op denorm-guarded libcall;
// softmax inputs are <= 8 and underflow-to-0 is harmless (row max term is always 2^0).
#define EXP2(x) __builtin_amdgcn_exp2f(x)

// cross-half (lane i <-> lane i^32) value pair via permlane32_swap intrinsic (SSA-safe).
__device__ __forceinline__ float2 xhalf_pair(float v) {
    uint2v r = __builtin_amdgcn_permlane32_swap(__float_as_uint(v), __float_as_uint(v), false, false);
    unsigned lo = r[0], hi = r[1];
    float2 out;
    out.x = __uint_as_float(lo);
    out.y = __uint_as_float(hi);
    return out;
}

// ---------------- f32 -> f16 conversion (q,k,v,Wq,Wk,Wv,Wo) + fused trig table ----------------
__global__ void k_cvt(const float* __restrict__ q, const float* __restrict__ k,
                      const float* __restrict__ v, const float* __restrict__ wq,
                      const float* __restrict__ wk, const float* __restrict__ wv,
                      const float* __restrict__ wo, f16* __restrict__ qh, f16* __restrict__ kh,
                      f16* __restrict__ vh, f16* __restrict__ wqh, f16* __restrict__ wkh,
                      f16* __restrict__ wvh, f16* __restrict__ woh,
                      const float* __restrict__ freqs, float2* __restrict__ csT) {
    int g = blockIdx.x * 256 + threadIdx.x;
    if (g >= 4194304) {  // trig tail: 65536 elems
        int i = g - 4194304;
        float f = freqs[i];
        float2 cs;
        cs.x = cosf(f);
        cs.y = sinf(f);
        csT[i] = cs;
        return;
    }
    const float* src;
    f16* dst;
    int base;
    if (g < 1048576)      { src = q;  dst = qh;  base = 0; }
    else if (g < 2097152) { src = k;  dst = kh;  base = 1048576; }
    else if (g < 3145728) { src = v;  dst = vh;  base = 2097152; }
    else if (g < 3407872) { src = wq; dst = wqh; base = 3145728; }
    else if (g < 3670016) { src = wk; dst = wkh; base = 3407872; }
    else if (g < 3932160) { src = wv; dst = wvh; base = 3670016; }
    else                  { src = wo; dst = woh; base = 3932160; }
    int i = g - base;
    float4 val = reinterpret_cast<const float4*>(src)[i];
    f16x4 o;
    o[0] = (f16)val.x; o[1] = (f16)val.y; o[2] = (f16)val.z; o[3] = (f16)val.w;
    reinterpret_cast<f16x4*>(dst)[i] = o;
}

// ---------------- shared GEMM main loop (BK=64, both-sides XOR swizzle, 128x128 tile) ----------
#define GEMM_MAINLOOP(A, W)                                                                  \
    const int tid = threadIdx.x;                                                             \
    const int lane = tid & 63, w = tid >> 6;                                                 \
    const int g = lane >> 4, r15 = lane & 15;                                                \
    const int m0 = blockIdx.x * 128, n0 = blockIdx.y * 128;                                  \
    const int wm = (w >> 1) * 64, wn = (w & 1) * 64;                                         \
    const f32x4 zero4 = {0.f, 0.f, 0.f, 0.f};                                                \
    f32x4 acc[4][4];                                                                         \
    _Pragma("unroll") for (int i = 0; i < 4; ++i) {                                          \
        _Pragma("unroll") for (int j = 0; j < 4; ++j) acc[i][j] = zero4;                     \
    }                                                                                        \
    const int srow0 = tid >> 3;                                                              \
    const int sj = tid & 7;                                                                  \
    for (int k0 = 0; k0 < Cd; k0 += 64) {                                                    \
        _Pragma("unroll") for (int c = 0; c < 4; ++c) {                                      \
            int row = c * 32 + srow0;                                                        \
            int ch = sj ^ (row & 7);                                                         \
            GLD_LDS16(A + (m0 + row) * Cd + k0 + ch * 8, Alds + (c * 256 + w * 64) * 8);     \
            GLD_LDS16(W + (n0 + row) * Cd + k0 + ch * 8, Blds + (c * 256 + w * 64) * 8);     \
        }                                                                                    \
        __syncthreads();                                                                     \
        _Pragma("unroll") for (int half = 0; half < 2; ++half) {                             \
            f16x8 af[4], bf[4];                                                              \
            _Pragma("unroll") for (int t = 0; t < 4; ++t) {                                  \
                int cidx = ((half << 2) | g) ^ (r15 & 7);                                    \
                af[t] = *(const f16x8*)&Alds[(wm + t * 16 + r15) * 64 + cidx * 8];           \
                bf[t] = *(const f16x8*)&Blds[(wn + t * 16 + r15) * 64 + cidx * 8];           \
            }                                                                                \
            _Pragma("unroll") for (int i = 0; i < 4; ++i) {                                  \
                _Pragma("unroll") for (int j = 0; j < 4; ++j) acc[i][j] =                    \
                    __builtin_amdgcn_mfma_f32_16x16x32_f16(af[i], bf[j], acc[i][j], 0, 0, 0); \
            }                                                                                \
        }                                                                                    \
        __syncthreads();                                                                     \
    }

// ---------------- fused QKV projection GEMM: z=0 Q(+rope), z=1 K(+rope), z=2 V(+transpose) ----
__global__ __launch_bounds__(256, 3) void k_gemm_qkv(
    const f16* __restrict__ qh, const f16* __restrict__ kh, const f16* __restrict__ vh,
    const f16* __restrict__ wqh, const f16* __restrict__ wkh, const f16* __restrict__ wvh,
    f16* __restrict__ Qp, f16* __restrict__ Kp, f16* __restrict__ Vt,
    const float2* __restrict__ csT) {
    __shared__ __attribute__((aligned(16))) char smem[34816];
    f16* Alds = (f16*)smem;
    f16* Blds = (f16*)(smem + 16384);
    const int z = blockIdx.z;
    const f16* A = (z == 0) ? qh : (z == 1) ? kh : vh;
    const f16* W = (z == 0) ? wqh : (z == 1) ? wkh : wvh;
    GEMM_MAINLOOP(A, W)
    if (z < 2) {
        f16* outp = z ? Kp : Qp;
#pragma unroll
        for (int i = 0; i < 4; ++i) {
#pragma unroll
            for (int j = 0; j < 4; ++j) {
#pragma unroll
                for (int r = 0; r < 4; ++r) {
                    int row = m0 + wm + i * 16 + g * 4 + r;
                    int col = n0 + wn + j * 16 + r15;
                    float own = acc[i][j][r];
                    float par = __shfl_xor(own, 1, 64);
                    float2 cs = csT[(row & 2047) * 32 + ((j * 16 + r15) >> 1)];
                    float val = (r15 & 1) ? fmaf(par, cs.y, own * cs.x)
                                          : fmaf(own, cs.x, -par * cs.y);
                    outp[row * Cd + col] = (f16)val;
                }
            }
        }
    } else {
        f16* Clds = (f16*)smem;
#pragma unroll
        for (int i = 0; i < 4; ++i) {
#pragma unroll
            for (int j = 0; j < 4; ++j) {
                f16x4 pv;
#pragma unroll
                for (int r = 0; r < 4; ++r) pv[r] = (f16)acc[i][j][r];
                *(f16x4*)&Clds[(wn + j * 16 + r15) * 136 + wm + i * 16 + g * 4] = pv;
            }
        }
        __syncthreads();
        const int orow = tid >> 1;
        const int th = (tid & 1) * 64;
        const int gcol = n0 + orow;
        const int hh = gcol >> 6, dd = gcol & 63;
        const int bb = m0 >> 11;
        f16* dst = Vt + ((bb * 16 + hh) * 64 + dd) * 2048 + (m0 & 2047) + th;
#pragma unroll
        for (int c = 0; c < 8; ++c) {
            f16x8 vv = *(const f16x8*)&Clds[orow * 136 + th + c * 8];
            *(f16x8*)&dst[c * 8] = vv;
        }
    }
}

// ---------------- output GEMM (f32 out), 128x64 tile -> 512 blocks = 2/CU ----------------
__global__ __launch_bounds__(256, 4) void k_gemm_out(const f16* __restrict__ yh,
                                                     const f16* __restrict__ woh,
                                                     float* __restrict__ out) {
    __shared__ __attribute__((aligned(16))) f16 Alds[128 * 64];
    __shared__ __attribute__((aligned(16))) f16 Blds[64 * 64];
    const int tid = threadIdx.x;
    const int lane = tid & 63, w = tid >> 6;
    const int g = lane >> 4, r15 = lane & 15;
    const int m0 = blockIdx.x * 128, n0 = blockIdx.y * 64;
    const int wm = (w >> 1) * 64, wn = (w & 1) * 32;
    const f32x4 zero4 = {0.f, 0.f, 0.f, 0.f};
    f32x4 acc[4][2];
#pragma unroll
    for (int i = 0; i < 4; ++i) {
#pragma unroll
        for (int j = 0; j < 2; ++j) acc[i][j] = zero4;
    }
    const int srow0 = tid >> 3;
    const int sj = tid & 7;
    for (int k0 = 0; k0 < Cd; k0 += 64) {
#pragma unroll
        for (int c = 0; c < 4; ++c) {
            int row = c * 32 + srow0;
            int ch = sj ^ (row & 7);
            GLD_LDS16(yh + (m0 + row) * Cd + k0 + ch * 8, (f16*)Alds + (c * 256 + w * 64) * 8);
        }
#pragma unroll
        for (int c = 0; c < 2; ++c) {
            int row = c * 32 + srow0;
            int ch = sj ^ (row & 7);
            GLD_LDS16(woh + (n0 + row) * Cd + k0 + ch * 8, (f16*)Blds + (c * 256 + w * 64) * 8);
        }
        __syncthreads();
#pragma unroll
        for (int half = 0; half < 2; ++half) {
            f16x8 af[4], bf[2];
            int cidx = ((half << 2) | g) ^ (r15 & 7);
#pragma unroll
            for (int t = 0; t < 4; ++t)
                af[t] = *(const f16x8*)&Alds[(wm + t * 16 + r15) * 64 + cidx * 8];
#pragma unroll
            for (int t = 0; t < 2; ++t)
                bf[t] = *(const f16x8*)&Blds[(wn + t * 16 + r15) * 64 + cidx * 8];
#pragma unroll
            for (int i = 0; i < 4; ++i) {
#pragma unroll
                for (int j = 0; j < 2; ++j)
                    acc[i][j] =
                        __builtin_amdgcn_mfma_f32_16x16x32_f16(af[i], bf[j], acc[i][j], 0, 0, 0);
            }
        }
        __syncthreads();
    }
#pragma unroll
    for (int i = 0; i < 4; ++i) {
#pragma unroll
        for (int j = 0; j < 2; ++j) {
#pragma unroll
            for (int r = 0; r < 4; ++r) {
                int row = m0 + wm + i * 16 + g * 4 + r;
                int col = n0 + wn + j * 16 + r15;
                out[row * Cd + col] = acc[i][j][r];
            }
        }
    }
}

// ---------------- Flash attention (R9 structure; only change: exp2f -> raw v_exp_f32) --------
__global__ __launch_bounds__(512, 4) void k_flash(const f16* __restrict__ Qp,
                                                  const f16* __restrict__ Kp,
                                                  const f16* __restrict__ Vt,
                                                  f16* __restrict__ y) {
    __shared__ __attribute__((aligned(16))) f16 Klds[2 * 2 * 4096];
    __shared__ __attribute__((aligned(16))) f16 Vlds[2 * 2 * 4096];
    const int bh = blockIdx.x, b = bh >> 4, h = bh & 15;
    const int tid = threadIdx.x, lane = tid & 63, w = tid >> 6;
    const int r31 = lane & 31, hi = lane >> 5;
    const int g2 = w >> 2, qw = w & 3;

    const int srow = tid >> 3, sj = tid & 7;
    const f16* gK = Kp + (b * 2048 + srow) * 1024 + h * 64 + ((sj ^ (srow & 7)) * 8);
    const f16* gV = Vt + (bh * 64 + srow) * 2048 + ((sj ^ (srow & 7)) * 8);
    f16* lK = (f16*)Klds + w * 512;
    f16* lV = (f16*)Vlds + w * 512;

#define STAGE_PAIR(pb, pi)                                          \
    do {                                                            \
        GLD_LDS16(gK + (2 * (pi)) * 65536, lK + (pb) * 8192);       \
        GLD_LDS16(gK + (2 * (pi) + 1) * 65536, lK + (pb) * 8192 + 4096); \
        GLD_LDS16(gV + (2 * (pi)) * 64, lV + (pb) * 8192);          \
        GLD_LDS16(gV + (2 * (pi) + 1) * 64, lV + (pb) * 8192 + 4096);   \
    } while (0)

    const int qrow = b * 2048 + blockIdx.y * 128 + qw * 32 + r31;
    f16x8 qf[4];
    {
        const f16* qb = Qp + qrow * 1024 + h * 64 + hi * 8;
        const f16 sc = (f16)(0.125f * 1.44269504088896f);
#pragma unroll
        for (int dc = 0; dc < 4; ++dc) {
            f16x8 v = *(const f16x8*)(qb + dc * 16);
#pragma unroll
            for (int j = 0; j < 8; ++j) v[j] = v[j] * sc;
            qf[dc] = v;
        }
    }

    f32x16 o0, o1;
#pragma unroll
    for (int r = 0; r < 16; ++r) { o0[r] = 0.f; o1[r] = 0.f; }
    float m = -1e30f, l = 0.f;

    STAGE_PAIR(0, 0);

    for (int it = 0; it < 16; ++it) {
        __builtin_amdgcn_s_barrier();
        if (it < 15) {
            STAGE_PAIR((it + 1) & 1, it + 1);
            asm volatile("s_waitcnt vmcnt(4)" ::: "memory");
        } else {
            asm volatile("s_waitcnt vmcnt(0)" ::: "memory");
        }
        __builtin_amdgcn_sched_barrier(0);
        __builtin_amdgcn_s_barrier();
        const f16* Kb = (const f16*)Klds + (it & 1) * 8192 + g2 * 4096;
        const f16* Vb = (const f16*)Vlds + (it & 1) * 8192 + g2 * 4096;

        f32x16 s0, s1;
#pragma unroll
        for (int r = 0; r < 16; ++r) { s0[r] = 0.f; s1[r] = 0.f; }
        __builtin_amdgcn_s_setprio(1);
#pragma unroll
        for (int dc = 0; dc < 4; ++dc) {
            int j = (2 * dc + hi) ^ (r31 & 7);
            f16x8 k0 = *(const f16x8*)&Kb[r31 * 64 + j * 8];
            f16x8 k1 = *(const f16x8*)&Kb[(32 + r31) * 64 + j * 8];
            s0 = __builtin_amdgcn_mfma_f32_32x32x16_f16(k0, qf[dc], s0, 0, 0, 0);
            s1 = __builtin_amdgcn_mfma_f32_32x32x16_f16(k1, qf[dc], s1, 0, 0, 0);
        }
        __builtin_amdgcn_s_setprio(0);

        float t16[16];
#pragma unroll
        for (int r = 0; r < 16; ++r) t16[r] = fmaxf(s0[r], s1[r]);
        float p0 = MAX3(t16[0], t16[1], t16[2]);
        float p1 = MAX3(t16[3], t16[4], t16[5]);
        float p2 = MAX3(t16[6], t16[7], t16[8]);
        float p3 = MAX3(t16[9], t16[10], t16[11]);
        float p4 = MAX3(t16[12], t16[13], t16[14]);
        float pmax = fmaxf(MAX3(p0, p1, p2), MAX3(p3, p4, t16[15]));
        {
            float2 pm = xhalf_pair(pmax);
            pmax = fmaxf(pm.x, pm.y);
        }
        if (__any(pmax > m + 8.0f)) {
            float mn = fmaxf(m, pmax);
            float cr = EXP2(m - mn);
            m = mn;
            l *= cr;
#pragma unroll
            for (int r = 0; r < 16; ++r) { o0[r] *= cr; o1[r] *= cr; }
        }
#pragma unroll
        for (int r = 0; r < 16; ++r) s0[r] = EXP2(s0[r] - m);
#pragma unroll
        for (int r = 0; r < 16; ++r) s1[r] = EXP2(s1[r] - m);
        float a16[16];
#pragma unroll
        for (int r = 0; r < 16; ++r) a16[r] = s0[r] + s1[r];
#pragma unroll
        for (int r = 0; r < 8; ++r) a16[r] += a16[r + 8];
#pragma unroll
        for (int r = 0; r < 4; ++r) a16[r] += a16[r + 4];
        float rs = (a16[0] + a16[1]) + (a16[2] + a16[3]);

        unsigned pk[16];
#pragma unroll
        for (int i = 0; i < 8; ++i) {
            auto ha = __builtin_amdgcn_cvt_pkrtz(s0[2 * i], s0[2 * i + 1]);
            __builtin_memcpy(&pk[i], &ha, 4);
            auto hb = __builtin_amdgcn_cvt_pkrtz(s1[2 * i], s1[2 * i + 1]);
            __builtin_memcpy(&pk[8 + i], &hb, 4);
        }

        __builtin_amdgcn_s_setprio(1);
#pragma unroll
        for (int s = 0; s < 4; ++s) {
            const int base = (s >> 1) * 8 + (s & 1) * 4;
            uint2v r0 = __builtin_amdgcn_permlane32_swap(pk[base + 0], pk[base + 2], false, false);
            uint2v r1 = __builtin_amdgcn_permlane32_swap(pk[base + 1], pk[base + 3], false, false);
            union { unsigned u[4]; f16x8 v; } uv;
            uv.u[0] = r0[0];
            uv.u[1] = r1[0];
            uv.u[2] = r0[1];
            uv.u[3] = r1[1];
            int j = (2 * s + hi) ^ (r31 & 7);
            f16x8 v0 = *(const f16x8*)&Vb[r31 * 64 + j * 8];
            f16x8 v1 = *(const f16x8*)&Vb[(32 + r31) * 64 + j * 8];
            o0 = __builtin_amdgcn_mfma_f32_32x32x16_f16(v0, uv.v, o0, 0, 0, 0);
            o1 = __builtin_amdgcn_mfma_f32_32x32x16_f16(v1, uv.v, o1, 0, 0, 0);
        }
        __builtin_amdgcn_s_setprio(0);

        {
            float2 rp = xhalf_pair(rs);
            l += rp.x + rp.y;
        }
    }
#undef STAGE_PAIR

    __syncthreads();
    float* Ko = (float*)Klds;
    float* Vm = (float*)Vlds;
    if (w >= 4) {
        const int slot = ((w - 4) * 64 + lane) * 32;
#pragma unroll
        for (int c = 0; c < 4; ++c) {
            f32x4 t;
#pragma unroll
            for (int i = 0; i < 4; ++i) t[i] = o0[c * 4 + i];
            *(f32x4*)&Ko[slot + c * 4] = t;
#pragma unroll
            for (int i = 0; i < 4; ++i) t[i] = o1[c * 4 + i];
            *(f32x4*)&Ko[slot + 16 + c * 4] = t;
        }
        Vm[((w - 4) * 64 + lane) * 2] = m;
        Vm[((w - 4) * 64 + lane) * 2 + 1] = l;
    }
    __syncthreads();
    if (w < 4) {
        const int slot = (w * 64 + lane) * 32;
        float mB = Vm[(w * 64 + lane) * 2];
        float lB = Vm[(w * 64 + lane) * 2 + 1];
        float mS = fmaxf(m, mB);
        float sA = EXP2(m - mS), sB = EXP2(mB - mS);
        float linv = 1.0f / (l * sA + lB * sB);
        sA *= linv;
        sB *= linv;
        f16* yb = y + qrow * 1024 + h * 64 + hi * 4;
#pragma unroll
        for (int rg = 0; rg < 4; ++rg) {
            f32x4 pB0 = *(const f32x4*)&Ko[slot + rg * 4];
            f32x4 pB1 = *(const f32x4*)&Ko[slot + 16 + rg * 4];
            f16x4 ov;
#pragma unroll
            for (int i = 0; i < 4; ++i) ov[i] = (f16)(o0[rg * 4 + i] * sA + pB0[i] * sB);
            *(f16x4*)&yb[rg * 8] = ov;
#pragma unroll
            for (int i = 0; i < 4; ++i) ov[i] = (f16)(o1[rg * 4 + i] * sA + pB1[i] * sB);
            *(f16x4*)&yb[32 + rg * 8] = ov;
        }
    }
}

extern "C" void kernel_launch(void* const* d_in, const int* in_sizes, int n_in, void* d_out,
                              int out_size, void* d_ws, size_t ws_size, hipStream_t stream) {
    const float* q = (const float*)d_in[0];
    const float* k = (const float*)d_in[1];
    const float* v = (const float*)d_in[2];
    const float* fr = (const float*)d_in[3];
    const float* wq = (const float*)d_in[4];
    const float* wk = (const float*)d_in[5];
    const float* wv = (const float*)d_in[6];
    const float* wo = (const float*)d_in[7];
    char* ws = (char*)d_ws;

    float2* csT = (float2*)(ws + 0);
    f16* qh = (f16*)(ws + 524288);
    f16* kh = (f16*)(ws + 8912896);
    f16* vh = (f16*)(ws + 17301504);
    f16* wqh = (f16*)(ws + 25690112);
    f16* wkh = (f16*)(ws + 27787264);
    f16* wvh = (f16*)(ws + 29884416);
    f16* woh = (f16*)(ws + 31981568);
    f16* Qp = (f16*)(ws + 34078720);
    f16* Kp = (f16*)(ws + 42467328);
    f16* Vt = (f16*)(ws + 50855936);
    f16* yh = (f16*)(ws + 8912896);  // aliases kh (dead after k_gemm_qkv)

    k_cvt<<<16640, 256, 0, stream>>>(q, k, v, wq, wk, wv, wo, qh, kh, vh, wqh, wkh, wvh, woh,
                                     fr, csT);
    dim3 gqkv(32, 8, 3);
    k_gemm_qkv<<<gqkv, 256, 0, stream>>>(qh, kh, vh, wqh, wkh, wvh, Qp, Kp, Vt, csT);
    dim3 gf(32, 16);
    k_flash<<<gf, 512, 0, stream>>>(Qp, Kp, Vt, yh);
    dim3 go(32, 16);
    k_gemm_out<<<go, 256, 0, stream>>>(yh, woh, (float*)d_out);
}